// Round 1
// baseline (1751.847 us; speedup 1.0000x reference)
//
#include <hip/hip_runtime.h>
#include <hip/hip_bf16.h>

#define NN 50000
#define EE 300000
#define ETOT (EE + NN)          // 350000 edges incl self-loops
#define GG 64
#define FDIM 64
#define HC 256                  // H*C
#define GCOLS 832               // 64 + 3*256
#define LATD 256

// ---------------- n0 = relu(bf @ bf_W + bf_b) ----------------
__global__ __launch_bounds__(256) void k_n0(const float* __restrict__ bf,
                                            const float* __restrict__ Wb,
                                            const float* __restrict__ bb,
                                            float* __restrict__ out) {
    int idx = blockIdx.x * 256 + threadIdx.x;
    if (idx >= NN * 64) return;
    int n = idx >> 6, j = idx & 63;
    float acc = bb[j];
    const float* r = bf + n * 5;
#pragma unroll
    for (int k = 0; k < 5; ++k) acc += r[k] * Wb[k * 64 + j];
    out[n * 64 + j] = fmaxf(acc, 0.f);
}

// ---------------- CSR build ----------------
__global__ __launch_bounds__(256) void k_count(const int* __restrict__ ei, int* __restrict__ counts) {
    int e = blockIdx.x * 256 + threadIdx.x;
    if (e >= ETOT) return;
    int d = (e < EE) ? ei[EE + e] : (e - EE);
    atomicAdd(&counts[d], 1);
}

__global__ __launch_bounds__(256) void k_scan_block(const int* __restrict__ counts, int* __restrict__ scanned,
                                                    int* __restrict__ bsums, int n) {
    __shared__ int sh[256];
    int i = blockIdx.x * 256 + threadIdx.x;
    int v = (i < n) ? counts[i] : 0;
    sh[threadIdx.x] = v; __syncthreads();
    for (int d = 1; d < 256; d <<= 1) {
        int t = (threadIdx.x >= d) ? sh[threadIdx.x - d] : 0;
        __syncthreads();
        sh[threadIdx.x] += t;
        __syncthreads();
    }
    if (i < n) scanned[i] = sh[threadIdx.x] - v;
    if (threadIdx.x == 255) bsums[blockIdx.x] = sh[255];
}

__global__ __launch_bounds__(256) void k_scan_sums(int* __restrict__ bsums, int nb) {
    __shared__ int sh[256];
    int v = (threadIdx.x < nb) ? bsums[threadIdx.x] : 0;
    sh[threadIdx.x] = v; __syncthreads();
    for (int d = 1; d < 256; d <<= 1) {
        int t = (threadIdx.x >= d) ? sh[threadIdx.x - d] : 0;
        __syncthreads();
        sh[threadIdx.x] += t;
        __syncthreads();
    }
    if (threadIdx.x < nb) bsums[threadIdx.x] = sh[threadIdx.x] - v;
}

__global__ __launch_bounds__(256) void k_scan_add(const int* __restrict__ scanned, const int* __restrict__ boffs,
                                                  int* __restrict__ indptr, int n, int total) {
    int i = blockIdx.x * 256 + threadIdx.x;
    if (i < n) indptr[i] = scanned[i] + boffs[i >> 8];
    if (i == 0) indptr[n] = total;
}

__global__ __launch_bounds__(256) void k_fill(const int* __restrict__ ei, const int* __restrict__ indptr,
                                              int* __restrict__ fill, int* __restrict__ esrc) {
    int e = blockIdx.x * 256 + threadIdx.x;
    if (e >= ETOT) return;
    int s, d;
    if (e < EE) { s = ei[e]; d = ei[EE + e]; } else { s = d = e - EE; }
    int pos = atomicAdd(&fill[d], 1);
    esrc[indptr[d] + pos] = s;
}

// ---------------- GEMM: Hout[M,256] = X[M,K] @ W[K,256] ----------------
__global__ __launch_bounds__(256) void k_gemm(const float* __restrict__ X, const float* __restrict__ W,
                                              float* __restrict__ Hout, int M, int K) {
    __shared__ float As[64][65];
    __shared__ float Ws[64][65];
    int row0 = blockIdx.x * 64, col0 = blockIdx.y * 64;
    int tid = threadIdx.x;
    int tr = (tid >> 4) << 2;
    int tc = (tid & 15) << 2;
    float acc[4][4] = {};
    for (int kt = 0; kt < K; kt += 64) {
#pragma unroll
        for (int i = 0; i < 16; ++i) {
            int idx = tid + i * 256;
            int r = idx >> 6, c = idx & 63;
            int gr = row0 + r;
            As[r][c] = (gr < M) ? X[(size_t)gr * K + kt + c] : 0.f;
            Ws[r][c] = W[(size_t)(kt + r) * 256 + col0 + c];
        }
        __syncthreads();
#pragma unroll
        for (int kk = 0; kk < 64; ++kk) {
            float a0 = As[tr][kk], a1 = As[tr + 1][kk], a2 = As[tr + 2][kk], a3 = As[tr + 3][kk];
            float b0 = Ws[kk][tc], b1 = Ws[kk][tc + 1], b2 = Ws[kk][tc + 2], b3 = Ws[kk][tc + 3];
            acc[0][0] += a0 * b0; acc[0][1] += a0 * b1; acc[0][2] += a0 * b2; acc[0][3] += a0 * b3;
            acc[1][0] += a1 * b0; acc[1][1] += a1 * b1; acc[1][2] += a1 * b2; acc[1][3] += a1 * b3;
            acc[2][0] += a2 * b0; acc[2][1] += a2 * b1; acc[2][2] += a2 * b2; acc[2][3] += a2 * b3;
            acc[3][0] += a3 * b0; acc[3][1] += a3 * b1; acc[3][2] += a3 * b2; acc[3][3] += a3 * b3;
        }
        __syncthreads();
    }
#pragma unroll
    for (int i = 0; i < 4; ++i) {
        int gr = row0 + tr + i;
        if (gr < M) {
#pragma unroll
            for (int j = 0; j < 4; ++j)
                Hout[(size_t)gr * 256 + col0 + tc + j] = acc[i][j];
        }
    }
}

// ---------------- a_s, a_d per node/head ----------------
__global__ __launch_bounds__(256) void k_asad(const float* __restrict__ Hbuf, const float* __restrict__ as,
                                              const float* __restrict__ ad, float* __restrict__ a_s,
                                              float* __restrict__ a_d) {
    int n = blockIdx.x;
    int w = threadIdx.x >> 6;     // head
    int l = threadIdx.x & 63;     // channel
    float hv = Hbuf[n * 256 + w * 64 + l];
    float vs = hv * as[w * 64 + l];
    float vd = hv * ad[w * 64 + l];
#pragma unroll
    for (int o = 32; o > 0; o >>= 1) {
        vs += __shfl_down(vs, o);
        vd += __shfl_down(vd, o);
    }
    if (l == 0) {
        a_s[n * 4 + w] = vs;
        a_d[n * 4 + w] = vd;
    }
}

// ---------------- per-dst-node softmax-aggregate (one wave per node) ----------------
__global__ __launch_bounds__(256) void k_agg(const float* __restrict__ Hbuf, const float* __restrict__ a_s,
                                             const float* __restrict__ a_d, const int* __restrict__ indptr,
                                             const int* __restrict__ esrc, const float* __restrict__ bias,
                                             float* __restrict__ out) {
    int wid = (blockIdx.x * 256 + threadIdx.x) >> 6;
    if (wid >= NN) return;
    int lane = threadIdx.x & 63;
    int head = lane >> 4;
    int beg = indptr[wid], end = indptr[wid + 1];
    float ad = a_d[wid * 4 + head];
    float mx = -1e30f;
    for (int e = beg; e < end; ++e) {
        int s = esrc[e];
        float el = a_s[s * 4 + head] + ad;
        el = el > 0.f ? el : 0.2f * el;
        mx = fmaxf(mx, el);
    }
    float ax = 0.f, ay = 0.f, az = 0.f, aw = 0.f, ssum = 0.f;
    for (int e = beg; e < end; ++e) {
        int s = esrc[e];
        float el = a_s[s * 4 + head] + ad;
        el = el > 0.f ? el : 0.2f * el;
        float p = __expf(el - mx);
        ssum += p;
        const float4 hv = *reinterpret_cast<const float4*>(Hbuf + (size_t)s * 256 + lane * 4);
        ax += p * hv.x; ay += p * hv.y; az += p * hv.z; aw += p * hv.w;
    }
    float inv = 1.0f / ssum;
    const float4 bv = *reinterpret_cast<const float4*>(bias + lane * 4);
    float4 o;
    o.x = fmaxf(ax * inv + bv.x, 0.f);
    o.y = fmaxf(ay * inv + bv.y, 0.f);
    o.z = fmaxf(az * inv + bv.z, 0.f);
    o.w = fmaxf(aw * inv + bv.w, 0.f);
    *reinterpret_cast<float4*>(out + (size_t)wid * 256 + lane * 4) = o;
}

// ---------------- pooling: int-bit atomicMax (all values >= 0 post-relu) ----------------
__global__ __launch_bounds__(256) void k_pool(const float* __restrict__ x, const int* __restrict__ batch,
                                              int* __restrict__ gbuf, int width, int ld, int off) {
    int idx = blockIdx.x * 256 + threadIdx.x;
    if (idx >= NN * width) return;
    int n = idx / width, c = idx % width;
    float v = x[n * ld + c];
    atomicMax(&gbuf[batch[n] * GCOLS + off + c], __float_as_int(v));
}

// ---------------- small dense layers ----------------
__global__ __launch_bounds__(256) void k_latent(const float* __restrict__ g, const float* __restrict__ W,
                                                const float* __restrict__ b, float* __restrict__ out) {
    int gi = blockIdx.x, j = threadIdx.x;
    float acc = b[j];
    const float* row = g + gi * GCOLS;
    for (int k = 0; k < GCOLS; ++k) acc += row[k] * W[k * 256 + j];
    out[gi * 256 + j] = acc;
}

__global__ __launch_bounds__(256) void k_proj(const float* __restrict__ x, const float* __restrict__ W,
                                              const float* __restrict__ b, float* __restrict__ out) {
    int gi = blockIdx.x, j = threadIdx.x;
    float acc = b[j];
    const float* row = x + gi * 256;
    for (int k = 0; k < 256; ++k) acc += row[k] * W[k * 256 + j];
    out[gi * 256 + j] = acc;
}

extern "C" void kernel_launch(void* const* d_in, const int* in_sizes, int n_in,
                              void* d_out, int out_size, void* d_ws, size_t ws_size,
                              hipStream_t stream) {
    const float* bf   = (const float*)d_in[0];
    const int*   ei   = (const int*)d_in[1];
    const int*   batch= (const int*)d_in[2];
    const float* bf_W = (const float*)d_in[3];
    const float* bf_b = (const float*)d_in[4];
    const float* W1   = (const float*)d_in[5];
    const float* as1  = (const float*)d_in[6];
    const float* ad1  = (const float*)d_in[7];
    const float* b1   = (const float*)d_in[8];
    const float* W2   = (const float*)d_in[9];
    const float* as2  = (const float*)d_in[10];
    const float* ad2  = (const float*)d_in[11];
    const float* b2   = (const float*)d_in[12];
    const float* W3   = (const float*)d_in[13];
    const float* as3  = (const float*)d_in[14];
    const float* ad3  = (const float*)d_in[15];
    const float* b3   = (const float*)d_in[16];
    const float* aggW = (const float*)d_in[17];
    const float* aggb = (const float*)d_in[18];
    const float* muW  = (const float*)d_in[19];
    const float* mub  = (const float*)d_in[20];
    const float* varW = (const float*)d_in[21];
    const float* varb = (const float*)d_in[22];
    float* out = (float*)d_out;

    // workspace layout
    size_t off = 0;
    auto alloc = [&](size_t bytes) -> char* {
        char* p = (char*)d_ws + off;
        off += (bytes + 255) & ~(size_t)255;
        return p;
    };
    float* bufA    = (float*)alloc((size_t)NN * 256 * 4);
    float* bufB    = (float*)alloc((size_t)NN * 256 * 4);
    float* a_s     = (float*)alloc((size_t)NN * 4 * 4);
    float* a_d     = (float*)alloc((size_t)NN * 4 * 4);
    int*   counts  = (int*)alloc((size_t)NN * 4);
    int*   scanned = (int*)alloc((size_t)NN * 4);
    int*   bsums   = (int*)alloc(256 * 4);
    int*   indptr  = (int*)alloc((size_t)(NN + 1) * 4);
    int*   fill    = (int*)alloc((size_t)NN * 4);
    int*   esrc    = (int*)alloc((size_t)ETOT * 4);
    int*   gbuf    = (int*)alloc((size_t)GG * GCOLS * 4);
    float* latent  = (float*)alloc((size_t)GG * 256 * 4);

    hipMemsetAsync(counts, 0, (size_t)NN * 4, stream);
    hipMemsetAsync(fill, 0, (size_t)NN * 4, stream);
    hipMemsetAsync(gbuf, 0, (size_t)GG * GCOLS * 4, stream);

    // n0
    k_n0<<<(NN * 64 + 255) / 256, 256, 0, stream>>>(bf, bf_W, bf_b, bufA);

    // CSR
    const int EB = (ETOT + 255) / 256;
    const int NB = (NN + 255) / 256;   // 196
    k_count<<<EB, 256, 0, stream>>>(ei, counts);
    k_scan_block<<<NB, 256, 0, stream>>>(counts, scanned, bsums, NN);
    k_scan_sums<<<1, 256, 0, stream>>>(bsums, NB);
    k_scan_add<<<NB, 256, 0, stream>>>(scanned, bsums, indptr, NN, ETOT);
    k_fill<<<EB, 256, 0, stream>>>(ei, indptr, fill, esrc);

    // pool n0
    k_pool<<<(NN * 64 + 255) / 256, 256, 0, stream>>>(bufA, batch, gbuf, 64, 64, 0);

    dim3 ggrid((NN + 63) / 64, 4);
    // ---- layer 1 (K=64) ----
    k_gemm<<<ggrid, 256, 0, stream>>>(bufA, W1, bufB, NN, 64);
    k_asad<<<NN, 256, 0, stream>>>(bufB, as1, ad1, a_s, a_d);
    k_agg<<<(NN + 3) / 4, 256, 0, stream>>>(bufB, a_s, a_d, indptr, esrc, b1, bufA);
    k_pool<<<(NN * 256 + 255) / 256, 256, 0, stream>>>(bufA, batch, gbuf, 256, 256, 64);

    // ---- layer 2 (K=256) ----
    k_gemm<<<ggrid, 256, 0, stream>>>(bufA, W2, bufB, NN, 256);
    k_asad<<<NN, 256, 0, stream>>>(bufB, as2, ad2, a_s, a_d);
    k_agg<<<(NN + 3) / 4, 256, 0, stream>>>(bufB, a_s, a_d, indptr, esrc, b2, bufA);
    k_pool<<<(NN * 256 + 255) / 256, 256, 0, stream>>>(bufA, batch, gbuf, 256, 256, 320);

    // ---- layer 3 (K=256) ----
    k_gemm<<<ggrid, 256, 0, stream>>>(bufA, W3, bufB, NN, 256);
    k_asad<<<NN, 256, 0, stream>>>(bufB, as3, ad3, a_s, a_d);
    k_agg<<<(NN + 3) / 4, 256, 0, stream>>>(bufB, a_s, a_d, indptr, esrc, b3, bufA);
    k_pool<<<(NN * 256 + 255) / 256, 256, 0, stream>>>(bufA, batch, gbuf, 256, 256, 576);

    // ---- head ----
    k_latent<<<GG, 256, 0, stream>>>((const float*)gbuf, aggW, aggb, latent);
    k_proj<<<GG, 256, 0, stream>>>(latent, muW, mub, out);
    k_proj<<<GG, 256, 0, stream>>>(latent, varW, varb, out + GG * 256);
}

// Round 2
// 566.068 us; speedup vs baseline: 3.0948x; 3.0948x over previous
//
#include <hip/hip_runtime.h>
#include <hip/hip_bf16.h>

#define NN 50000
#define NPAD 50048              // 391 * 128
#define EE 300000
#define ETOT (EE + NN)          // 350000 edges incl self-loops
#define GG 64
#define GCOLS 832               // 64 + 3*256
#define BM 128
#define BN 128

typedef unsigned short u16;
typedef short s16x8 __attribute__((ext_vector_type(8)));
typedef float f32x4 __attribute__((ext_vector_type(4)));

__device__ __forceinline__ u16 f2bf(float f) {
    union { float f; unsigned u; } v; v.f = f;
    unsigned r = v.u + 0x7FFFu + ((v.u >> 16) & 1u);
    return (u16)(r >> 16);
}
__device__ __forceinline__ float bf2f(u16 u) {
    union { unsigned u; float f; } v; v.u = ((unsigned)u) << 16;
    return v.f;
}

// ---------------- weight transpose + bf16 convert: Wt[n][k] = bf(W[k][n]) ----------------
__global__ __launch_bounds__(256) void k_wt(const float* __restrict__ W, u16* __restrict__ Wt, int K) {
    int idx = blockIdx.x * 256 + threadIdx.x;
    if (idx >= 256 * K) return;
    int n = idx / K, k = idx % K;
    Wt[idx] = f2bf(W[k * 256 + n]);
}

// ---------------- n0 = relu(bf @ bf_W + bf_b), f32 + bf16 mirror ----------------
__global__ __launch_bounds__(256) void k_n0(const float* __restrict__ bf,
                                            const float* __restrict__ Wb,
                                            const float* __restrict__ bb,
                                            float* __restrict__ out,
                                            u16* __restrict__ outbf) {
    int idx = blockIdx.x * 256 + threadIdx.x;
    if (idx >= NN * 64) return;
    int n = idx >> 6, j = idx & 63;
    float acc = bb[j];
    const float* r = bf + n * 5;
#pragma unroll
    for (int k = 0; k < 5; ++k) acc += r[k] * Wb[k * 64 + j];
    float v = fmaxf(acc, 0.f);
    out[idx] = v;
    outbf[idx] = f2bf(v);
}

// ---------------- CSR build ----------------
__global__ __launch_bounds__(256) void k_count(const int* __restrict__ ei, int* __restrict__ counts) {
    int e = blockIdx.x * 256 + threadIdx.x;
    if (e >= ETOT) return;
    int d = (e < EE) ? ei[EE + e] : (e - EE);
    atomicAdd(&counts[d], 1);
}

__global__ __launch_bounds__(256) void k_scan_block(const int* __restrict__ counts, int* __restrict__ scanned,
                                                    int* __restrict__ bsums, int n) {
    __shared__ int sh[256];
    int i = blockIdx.x * 256 + threadIdx.x;
    int v = (i < n) ? counts[i] : 0;
    sh[threadIdx.x] = v; __syncthreads();
    for (int d = 1; d < 256; d <<= 1) {
        int t = (threadIdx.x >= d) ? sh[threadIdx.x - d] : 0;
        __syncthreads();
        sh[threadIdx.x] += t;
        __syncthreads();
    }
    if (i < n) scanned[i] = sh[threadIdx.x] - v;
    if (threadIdx.x == 255) bsums[blockIdx.x] = sh[255];
}

__global__ __launch_bounds__(256) void k_scan_sums(int* __restrict__ bsums, int nb) {
    __shared__ int sh[256];
    int v = (threadIdx.x < nb) ? bsums[threadIdx.x] : 0;
    sh[threadIdx.x] = v; __syncthreads();
    for (int d = 1; d < 256; d <<= 1) {
        int t = (threadIdx.x >= d) ? sh[threadIdx.x - d] : 0;
        __syncthreads();
        sh[threadIdx.x] += t;
        __syncthreads();
    }
    if (threadIdx.x < nb) bsums[threadIdx.x] = sh[threadIdx.x] - v;
}

__global__ __launch_bounds__(256) void k_scan_add(const int* __restrict__ scanned, const int* __restrict__ boffs,
                                                  int* __restrict__ indptr, int n, int total) {
    int i = blockIdx.x * 256 + threadIdx.x;
    if (i < n) indptr[i] = scanned[i] + boffs[i >> 8];
    if (i == 0) indptr[n] = total;
}

__global__ __launch_bounds__(256) void k_fill(const int* __restrict__ ei, const int* __restrict__ indptr,
                                              int* __restrict__ fill, int* __restrict__ esrc) {
    int e = blockIdx.x * 256 + threadIdx.x;
    if (e >= ETOT) return;
    int s, d;
    if (e < EE) { s = ei[e]; d = ei[EE + e]; } else { s = d = e - EE; }
    int pos = atomicAdd(&fill[d], 1);
    esrc[indptr[d] + pos] = s;
}

// ---------------- bf16 MFMA GEMM: Hout[M,256](f32) = A[M,K](bf16) @ Wt[256,K]^T(bf16) ----------------
// 128x128 tile, BK=64, 4 waves (2x2), each wave 64x64 out = 4x4 frags of 16x16x32.
// LDS tiles row-major [rows][64] bf16 with XOR swizzle: 16B slot c16 stored at c16^(r&7).
__global__ __launch_bounds__(256) void k_gemm_mfma(const u16* __restrict__ A,
                                                   const u16* __restrict__ Bt,
                                                   float* __restrict__ Hout,
                                                   int K) {
    __shared__ __align__(16) u16 As[128 * 64];
    __shared__ __align__(16) u16 Bs[128 * 64];
    const int tid = threadIdx.x;
    const int lane = tid & 63;
    const int w = tid >> 6;
    const int wr = w >> 1, wc = w & 1;
    const int row0 = blockIdx.x * BM;
    const int col0 = blockIdx.y * BN;

    f32x4 acc[4][4] = {};

    for (int kt = 0; kt < K; kt += 64) {
#pragma unroll
        for (int i = 0; i < 4; ++i) {
            int u = i * 256 + tid;
            int r = u >> 3, c16 = u & 7;
            int sc = ((c16 ^ (r & 7)) << 3);
            const u16* ga = A + (size_t)(row0 + r) * K + kt + sc;
            u16* la = &As[(size_t)(i * 256 + (w << 6)) * 8];
            __builtin_amdgcn_global_load_lds((const __attribute__((address_space(1))) void*)ga,
                                             (__attribute__((address_space(3))) void*)la, 16, 0, 0);
        }
#pragma unroll
        for (int i = 0; i < 4; ++i) {
            int u = i * 256 + tid;
            int r = u >> 3, c16 = u & 7;
            int sc = ((c16 ^ (r & 7)) << 3);
            const u16* gb = Bt + (size_t)(col0 + r) * K + kt + sc;
            u16* lb = &Bs[(size_t)(i * 256 + (w << 6)) * 8];
            __builtin_amdgcn_global_load_lds((const __attribute__((address_space(1))) void*)gb,
                                             (__attribute__((address_space(3))) void*)lb, 16, 0, 0);
        }
        __syncthreads();
#pragma unroll
        for (int ks = 0; ks < 2; ++ks) {
            s16x8 af[4], bfr[4];
#pragma unroll
            for (int m = 0; m < 4; ++m) {
                int ra = wr * 64 + m * 16 + (lane & 15);
                int c16 = ks * 4 + (lane >> 4);
                int off = ra * 64 + ((c16 ^ (ra & 7)) << 3);
                af[m] = *reinterpret_cast<const s16x8*>(&As[off]);
            }
#pragma unroll
            for (int n = 0; n < 4; ++n) {
                int rb = wc * 64 + n * 16 + (lane & 15);
                int c16 = ks * 4 + (lane >> 4);
                int off = rb * 64 + ((c16 ^ (rb & 7)) << 3);
                bfr[n] = *reinterpret_cast<const s16x8*>(&Bs[off]);
            }
#pragma unroll
            for (int m = 0; m < 4; ++m)
#pragma unroll
                for (int n = 0; n < 4; ++n)
                    acc[m][n] = __builtin_amdgcn_mfma_f32_16x16x32_bf16(af[m], bfr[n], acc[m][n], 0, 0, 0);
        }
        __syncthreads();
    }
#pragma unroll
    for (int m = 0; m < 4; ++m) {
        int grow = row0 + wr * 64 + m * 16 + (lane >> 4) * 4;
#pragma unroll
        for (int j = 0; j < 4; ++j) {
            float* orow = Hout + (size_t)(grow + j) * 256 + col0 + wc * 64 + (lane & 15);
#pragma unroll
            for (int n = 0; n < 4; ++n)
                orow[n * 16] = acc[m][n][j];
        }
    }
}

// ---------------- a_s, a_d per node/head ----------------
__global__ __launch_bounds__(256) void k_asad(const float* __restrict__ Hbuf, const float* __restrict__ as,
                                              const float* __restrict__ ad, float* __restrict__ a_s,
                                              float* __restrict__ a_d) {
    int n = blockIdx.x;
    int w = threadIdx.x >> 6;     // head
    int l = threadIdx.x & 63;     // channel
    float hv = Hbuf[n * 256 + w * 64 + l];
    float vs = hv * as[w * 64 + l];
    float vd = hv * ad[w * 64 + l];
#pragma unroll
    for (int o = 32; o > 0; o >>= 1) {
        vs += __shfl_down(vs, o);
        vd += __shfl_down(vd, o);
    }
    if (l == 0) {
        a_s[n * 4 + w] = vs;
        a_d[n * 4 + w] = vd;
    }
}

// ---------------- per-dst-node softmax-aggregate (one wave per node), bf16 out ----------------
__global__ __launch_bounds__(256) void k_agg(const float* __restrict__ Hbuf, const float* __restrict__ a_s,
                                             const float* __restrict__ a_d, const int* __restrict__ indptr,
                                             const int* __restrict__ esrc, const float* __restrict__ bias,
                                             u16* __restrict__ outbf) {
    int wid = (blockIdx.x * 256 + threadIdx.x) >> 6;
    if (wid >= NN) return;
    int lane = threadIdx.x & 63;
    int head = lane >> 4;
    int beg = indptr[wid], end = indptr[wid + 1];
    float ad = a_d[wid * 4 + head];
    float mx = -1e30f;
    for (int e = beg; e < end; ++e) {
        int s = esrc[e];
        float el = a_s[s * 4 + head] + ad;
        el = el > 0.f ? el : 0.2f * el;
        mx = fmaxf(mx, el);
    }
    float ax = 0.f, ay = 0.f, az = 0.f, aw = 0.f, ssum = 0.f;
    for (int e = beg; e < end; ++e) {
        int s = esrc[e];
        float el = a_s[s * 4 + head] + ad;
        el = el > 0.f ? el : 0.2f * el;
        float p = __expf(el - mx);
        ssum += p;
        const float4 hv = *reinterpret_cast<const float4*>(Hbuf + (size_t)s * 256 + lane * 4);
        ax += p * hv.x; ay += p * hv.y; az += p * hv.z; aw += p * hv.w;
    }
    float inv = 1.0f / ssum;
    const float4 bv = *reinterpret_cast<const float4*>(bias + lane * 4);
    ushort4 ob;
    ob.x = f2bf(fmaxf(ax * inv + bv.x, 0.f));
    ob.y = f2bf(fmaxf(ay * inv + bv.y, 0.f));
    ob.z = f2bf(fmaxf(az * inv + bv.z, 0.f));
    ob.w = f2bf(fmaxf(aw * inv + bv.w, 0.f));
    *reinterpret_cast<ushort4*>(outbf + (size_t)wid * 256 + lane * 4) = ob;
}

// ---------------- pooling, f32 input (n0, width 64) ----------------
__global__ __launch_bounds__(256) void k_pool_f32(const float* __restrict__ x, const int* __restrict__ batch,
                                                  int* __restrict__ gbuf, int off) {
    const int width = 64, S = 4;
    int c = threadIdx.x & 63;
    int sub = threadIdx.x >> 6;
    int base = blockIdx.x * 128;
    int end = min(base + 128, NN);
    float mx = 0.f;
    int curg = -1;
    for (int n = base + sub; n < end; n += S) {
        int g = batch[n];
        float v = x[(size_t)n * width + c];
        if (g != curg) {
            if (curg >= 0) atomicMax(&gbuf[curg * GCOLS + off + c], __float_as_int(mx));
            mx = 0.f; curg = g;
        }
        mx = fmaxf(mx, v);
    }
    if (curg >= 0) atomicMax(&gbuf[curg * GCOLS + off + c], __float_as_int(mx));
}

// ---------------- pooling, bf16 input (layers, width 256) ----------------
__global__ __launch_bounds__(256) void k_pool_bf(const u16* __restrict__ x, const int* __restrict__ batch,
                                                 int* __restrict__ gbuf, int off) {
    int c = threadIdx.x;
    int base = blockIdx.x * 128;
    int end = min(base + 128, NN);
    float mx = 0.f;
    int curg = -1;
    for (int n = base; n < end; ++n) {
        int g = batch[n];
        float v = bf2f(x[(size_t)n * 256 + c]);
        if (g != curg) {
            if (curg >= 0) atomicMax(&gbuf[curg * GCOLS + off + c], __float_as_int(mx));
            mx = 0.f; curg = g;
        }
        mx = fmaxf(mx, v);
    }
    if (curg >= 0) atomicMax(&gbuf[curg * GCOLS + off + c], __float_as_int(mx));
}

// ---------------- small dense layers ----------------
__global__ __launch_bounds__(256) void k_latent(const float* __restrict__ g, const float* __restrict__ W,
                                                const float* __restrict__ b, float* __restrict__ out) {
    int gi = blockIdx.x, j = threadIdx.x;
    float acc = b[j];
    const float* row = g + gi * GCOLS;
    for (int k = 0; k < GCOLS; ++k) acc += row[k] * W[k * 256 + j];
    out[gi * 256 + j] = acc;
}

__global__ __launch_bounds__(256) void k_proj(const float* __restrict__ x, const float* __restrict__ W,
                                              const float* __restrict__ b, float* __restrict__ out) {
    int gi = blockIdx.x, j = threadIdx.x;
    float acc = b[j];
    const float* row = x + gi * 256;
    for (int k = 0; k < 256; ++k) acc += row[k] * W[k * 256 + j];
    out[gi * 256 + j] = acc;
}

extern "C" void kernel_launch(void* const* d_in, const int* in_sizes, int n_in,
                              void* d_out, int out_size, void* d_ws, size_t ws_size,
                              hipStream_t stream) {
    const float* bf   = (const float*)d_in[0];
    const int*   ei   = (const int*)d_in[1];
    const int*   batch= (const int*)d_in[2];
    const float* bf_W = (const float*)d_in[3];
    const float* bf_b = (const float*)d_in[4];
    const float* W1   = (const float*)d_in[5];
    const float* as1  = (const float*)d_in[6];
    const float* ad1  = (const float*)d_in[7];
    const float* b1   = (const float*)d_in[8];
    const float* W2   = (const float*)d_in[9];
    const float* as2  = (const float*)d_in[10];
    const float* ad2  = (const float*)d_in[11];
    const float* b2   = (const float*)d_in[12];
    const float* W3   = (const float*)d_in[13];
    const float* as3  = (const float*)d_in[14];
    const float* ad3  = (const float*)d_in[15];
    const float* b3   = (const float*)d_in[16];
    const float* aggW = (const float*)d_in[17];
    const float* aggb = (const float*)d_in[18];
    const float* muW  = (const float*)d_in[19];
    const float* mub  = (const float*)d_in[20];
    const float* varW = (const float*)d_in[21];
    const float* varb = (const float*)d_in[22];
    float* out = (float*)d_out;

    size_t off = 0;
    auto alloc = [&](size_t bytes) -> char* {
        char* p = (char*)d_ws + off;
        off += (bytes + 255) & ~(size_t)255;
        return p;
    };
    float* Hbuf    = (float*)alloc((size_t)NPAD * 256 * 4);   // gemm out (f32)
    float* n0f     = (float*)alloc((size_t)NN * 64 * 4);      // n0 f32 (exact pooling)
    u16*   n0bf    = (u16*)alloc((size_t)NPAD * 64 * 2);      // n0 bf16 (gemm1 in)
    u16*   nbf     = (u16*)alloc((size_t)NPAD * 256 * 2);     // layer activations bf16
    float* a_s     = (float*)alloc((size_t)NN * 4 * 4);
    float* a_d     = (float*)alloc((size_t)NN * 4 * 4);
    int*   counts  = (int*)alloc((size_t)NN * 4);
    int*   scanned = (int*)alloc((size_t)NN * 4);
    int*   bsums   = (int*)alloc(256 * 4);
    int*   indptr  = (int*)alloc((size_t)(NN + 1) * 4);
    int*   fill    = (int*)alloc((size_t)NN * 4);
    int*   esrc    = (int*)alloc((size_t)ETOT * 4);
    int*   gbuf    = (int*)alloc((size_t)GG * GCOLS * 4);
    float* latent  = (float*)alloc((size_t)GG * 256 * 4);
    u16*   Wt1     = (u16*)alloc((size_t)256 * 64 * 2);
    u16*   Wt2     = (u16*)alloc((size_t)256 * 256 * 2);
    u16*   Wt3     = (u16*)alloc((size_t)256 * 256 * 2);

    hipMemsetAsync(counts, 0, (size_t)NN * 4, stream);
    hipMemsetAsync(fill, 0, (size_t)NN * 4, stream);
    hipMemsetAsync(gbuf, 0, (size_t)GG * GCOLS * 4, stream);
    // zero bf16 pad rows (read by gemm staging)
    hipMemsetAsync(n0bf + (size_t)NN * 64, 0, (size_t)(NPAD - NN) * 64 * 2, stream);
    hipMemsetAsync(nbf + (size_t)NN * 256, 0, (size_t)(NPAD - NN) * 256 * 2, stream);

    // weight transposes
    k_wt<<<(256 * 64 + 255) / 256, 256, 0, stream>>>(W1, Wt1, 64);
    k_wt<<<(256 * 256 + 255) / 256, 256, 0, stream>>>(W2, Wt2, 256);
    k_wt<<<(256 * 256 + 255) / 256, 256, 0, stream>>>(W3, Wt3, 256);

    // n0
    k_n0<<<(NN * 64 + 255) / 256, 256, 0, stream>>>(bf, bf_W, bf_b, n0f, n0bf);

    // CSR
    const int EB = (ETOT + 255) / 256;
    const int NB = (NN + 255) / 256;
    k_count<<<EB, 256, 0, stream>>>(ei, counts);
    k_scan_block<<<NB, 256, 0, stream>>>(counts, scanned, bsums, NN);
    k_scan_sums<<<1, 256, 0, stream>>>(bsums, NB);
    k_scan_add<<<NB, 256, 0, stream>>>(scanned, bsums, indptr, NN, ETOT);
    k_fill<<<EB, 256, 0, stream>>>(ei, indptr, fill, esrc);

    const int PB = (NN + 127) / 128;  // 391
    k_pool_f32<<<PB, 256, 0, stream>>>(n0f, batch, gbuf, 0);

    dim3 ggrid(NPAD / BM, 256 / BN);  // (391, 2)
    // ---- layer 1 (K=64) ----
    k_gemm_mfma<<<ggrid, 256, 0, stream>>>(n0bf, Wt1, Hbuf, 64);
    k_asad<<<NN, 256, 0, stream>>>(Hbuf, as1, ad1, a_s, a_d);
    k_agg<<<(NN + 3) / 4, 256, 0, stream>>>(Hbuf, a_s, a_d, indptr, esrc, b1, nbf);
    k_pool_bf<<<PB, 256, 0, stream>>>(nbf, batch, gbuf, 64);

    // ---- layer 2 (K=256) ----
    k_gemm_mfma<<<ggrid, 256, 0, stream>>>(nbf, Wt2, Hbuf, 256);
    k_asad<<<NN, 256, 0, stream>>>(Hbuf, as2, ad2, a_s, a_d);
    k_agg<<<(NN + 3) / 4, 256, 0, stream>>>(Hbuf, a_s, a_d, indptr, esrc, b2, nbf);
    k_pool_bf<<<PB, 256, 0, stream>>>(nbf, batch, gbuf, 320);

    // ---- layer 3 (K=256) ----
    k_gemm_mfma<<<ggrid, 256, 0, stream>>>(nbf, Wt3, Hbuf, 256);
    k_asad<<<NN, 256, 0, stream>>>(Hbuf, as3, ad3, a_s, a_d);
    k_agg<<<(NN + 3) / 4, 256, 0, stream>>>(Hbuf, a_s, a_d, indptr, esrc, b3, nbf);
    k_pool_bf<<<PB, 256, 0, stream>>>(nbf, batch, gbuf, 576);

    // ---- head ----
    k_latent<<<GG, 256, 0, stream>>>((const float*)gbuf, aggW, aggb, latent);
    k_proj<<<GG, 256, 0, stream>>>(latent, muW, mub, out);
    k_proj<<<GG, 256, 0, stream>>>(latent, varW, varb, out + GG * 256);
}

// Round 3
// 429.698 us; speedup vs baseline: 4.0769x; 1.3174x over previous
//
#include <hip/hip_runtime.h>
#include <hip/hip_bf16.h>

#define NN 50000
#define NPAD 50048              // 391 * 128
#define EE 300000
#define ETOT (EE + NN)          // 350000 edges incl self-loops
#define GG 64
#define GCOLS 832               // 64 + 3*256
#define BM 128
#define BN 128

typedef unsigned short u16;
typedef short s16x8 __attribute__((ext_vector_type(8)));
typedef float f32x4 __attribute__((ext_vector_type(4)));

__device__ __forceinline__ u16 f2bf(float f) {
    union { float f; unsigned u; } v; v.f = f;
    unsigned r = v.u + 0x7FFFu + ((v.u >> 16) & 1u);
    return (u16)(r >> 16);
}
__device__ __forceinline__ float bf2f(u16 u) {
    union { unsigned u; float f; } v; v.u = ((unsigned)u) << 16;
    return v.f;
}

// ---------------- weight transpose + bf16 convert: Wt[n][k] = bf(W[k][n]) ----------------
__global__ __launch_bounds__(256) void k_wt(const float* __restrict__ W, u16* __restrict__ Wt, int K) {
    int idx = blockIdx.x * 256 + threadIdx.x;
    if (idx >= 256 * K) return;
    int n = idx / K, k = idx % K;
    Wt[idx] = f2bf(W[k * 256 + n]);
}

// ---------------- n0 = relu(bf @ bf_W + bf_b), f32 + bf16 mirror ----------------
__global__ __launch_bounds__(256) void k_n0(const float* __restrict__ bf,
                                            const float* __restrict__ Wb,
                                            const float* __restrict__ bb,
                                            float* __restrict__ out,
                                            u16* __restrict__ outbf) {
    int idx = blockIdx.x * 256 + threadIdx.x;
    if (idx >= NN * 64) return;
    int n = idx >> 6, j = idx & 63;
    float acc = bb[j];
    const float* r = bf + n * 5;
#pragma unroll
    for (int k = 0; k < 5; ++k) acc += r[k] * Wb[k * 64 + j];
    float v = fmaxf(acc, 0.f);
    out[idx] = v;
    outbf[idx] = f2bf(v);
}

// ---------------- CSR build ----------------
__global__ __launch_bounds__(256) void k_count(const int* __restrict__ ei, int* __restrict__ counts) {
    int e = blockIdx.x * 256 + threadIdx.x;
    if (e >= ETOT) return;
    int d = (e < EE) ? ei[EE + e] : (e - EE);
    atomicAdd(&counts[d], 1);
}

__global__ __launch_bounds__(256) void k_scan_block(const int* __restrict__ counts, int* __restrict__ scanned,
                                                    int* __restrict__ bsums, int n) {
    __shared__ int sh[256];
    int i = blockIdx.x * 256 + threadIdx.x;
    int v = (i < n) ? counts[i] : 0;
    sh[threadIdx.x] = v; __syncthreads();
    for (int d = 1; d < 256; d <<= 1) {
        int t = (threadIdx.x >= d) ? sh[threadIdx.x - d] : 0;
        __syncthreads();
        sh[threadIdx.x] += t;
        __syncthreads();
    }
    if (i < n) scanned[i] = sh[threadIdx.x] - v;
    if (threadIdx.x == 255) bsums[blockIdx.x] = sh[255];
}

__global__ __launch_bounds__(256) void k_scan_sums(int* __restrict__ bsums, int nb) {
    __shared__ int sh[256];
    int v = (threadIdx.x < nb) ? bsums[threadIdx.x] : 0;
    sh[threadIdx.x] = v; __syncthreads();
    for (int d = 1; d < 256; d <<= 1) {
        int t = (threadIdx.x >= d) ? sh[threadIdx.x - d] : 0;
        __syncthreads();
        sh[threadIdx.x] += t;
        __syncthreads();
    }
    if (threadIdx.x < nb) bsums[threadIdx.x] = sh[threadIdx.x] - v;
}

__global__ __launch_bounds__(256) void k_scan_add(const int* __restrict__ scanned, const int* __restrict__ boffs,
                                                  int* __restrict__ indptr, int n, int total) {
    int i = blockIdx.x * 256 + threadIdx.x;
    if (i < n) indptr[i] = scanned[i] + boffs[i >> 8];
    if (i == 0) indptr[n] = total;
}

__global__ __launch_bounds__(256) void k_fill(const int* __restrict__ ei, const int* __restrict__ indptr,
                                              int* __restrict__ fill, int* __restrict__ esrc) {
    int e = blockIdx.x * 256 + threadIdx.x;
    if (e >= ETOT) return;
    int s, d;
    if (e < EE) { s = ei[e]; d = ei[EE + e]; } else { s = d = e - EE; }
    int pos = atomicAdd(&fill[d], 1);
    esrc[indptr[d] + pos] = s;
}

// ---------------- bf16 MFMA GEMM + fused a_s/a_d epilogue ----------------
// Hbf[M,256](bf16) = A[M,K](bf16) @ Wt[256,K]^T(bf16)
// a_s[n,head] = sum_c h[n,head,c]*att_s[head,c]  (from f32 acc, per-wave head)
// 128x128 tile, BK=64, 4 waves (2x2), each wave 64x64 out = 4x4 frags of 16x16x32.
__global__ __launch_bounds__(256) void k_gemm_mfma(const u16* __restrict__ A,
                                                   const u16* __restrict__ Bt,
                                                   const float* __restrict__ att_s,
                                                   const float* __restrict__ att_d,
                                                   u16* __restrict__ Hbf,
                                                   float* __restrict__ a_s,
                                                   float* __restrict__ a_d,
                                                   int K) {
    __shared__ __align__(16) u16 As[128 * 64];
    __shared__ __align__(16) u16 Bs[128 * 64];
    const int tid = threadIdx.x;
    const int lane = tid & 63;
    const int w = tid >> 6;
    const int wr = w >> 1, wc = w & 1;
    const int row0 = blockIdx.x * BM;
    const int col0 = blockIdx.y * BN;

    f32x4 acc[4][4] = {};

    for (int kt = 0; kt < K; kt += 64) {
#pragma unroll
        for (int i = 0; i < 4; ++i) {
            int u = i * 256 + tid;
            int r = u >> 3, c16 = u & 7;
            int sc = ((c16 ^ (r & 7)) << 3);
            const u16* ga = A + (size_t)(row0 + r) * K + kt + sc;
            u16* la = &As[(size_t)(i * 256 + (w << 6)) * 8];
            __builtin_amdgcn_global_load_lds((const __attribute__((address_space(1))) void*)ga,
                                             (__attribute__((address_space(3))) void*)la, 16, 0, 0);
        }
#pragma unroll
        for (int i = 0; i < 4; ++i) {
            int u = i * 256 + tid;
            int r = u >> 3, c16 = u & 7;
            int sc = ((c16 ^ (r & 7)) << 3);
            const u16* gb = Bt + (size_t)(col0 + r) * K + kt + sc;
            u16* lb = &Bs[(size_t)(i * 256 + (w << 6)) * 8];
            __builtin_amdgcn_global_load_lds((const __attribute__((address_space(1))) void*)gb,
                                             (__attribute__((address_space(3))) void*)lb, 16, 0, 0);
        }
        __syncthreads();
#pragma unroll
        for (int ks = 0; ks < 2; ++ks) {
            s16x8 af[4], bfr[4];
#pragma unroll
            for (int m = 0; m < 4; ++m) {
                int ra = wr * 64 + m * 16 + (lane & 15);
                int c16 = ks * 4 + (lane >> 4);
                int off = ra * 64 + ((c16 ^ (ra & 7)) << 3);
                af[m] = *reinterpret_cast<const s16x8*>(&As[off]);
            }
#pragma unroll
            for (int n = 0; n < 4; ++n) {
                int rb = wc * 64 + n * 16 + (lane & 15);
                int c16 = ks * 4 + (lane >> 4);
                int off = rb * 64 + ((c16 ^ (rb & 7)) << 3);
                bfr[n] = *reinterpret_cast<const s16x8*>(&Bs[off]);
            }
#pragma unroll
            for (int m = 0; m < 4; ++m)
#pragma unroll
                for (int n = 0; n < 4; ++n)
                    acc[m][n] = __builtin_amdgcn_mfma_f32_16x16x32_bf16(af[m], bfr[n], acc[m][n], 0, 0, 0);
        }
        __syncthreads();
    }

    // ---- epilogue: bf16 H store + fused per-head a_s/a_d reduction ----
    const int head = (blockIdx.y << 1) + wc;       // this wave's 64 cols = one head
    float asv[4], adv[4];
#pragma unroll
    for (int n = 0; n < 4; ++n) {
        asv[n] = att_s[head * 64 + n * 16 + (lane & 15)];
        adv[n] = att_d[head * 64 + n * 16 + (lane & 15)];
    }
#pragma unroll
    for (int m = 0; m < 4; ++m) {
        int growb = row0 + wr * 64 + m * 16 + (lane >> 4) * 4;
#pragma unroll
        for (int j = 0; j < 4; ++j) {
            int grow = growb + j;
            u16* orow = Hbf + (size_t)grow * 256 + col0 + wc * 64 + (lane & 15);
            float vs = 0.f, vd = 0.f;
#pragma unroll
            for (int n = 0; n < 4; ++n) {
                float v = acc[m][n][j];
                orow[n * 16] = f2bf(v);
                vs += v * asv[n];
                vd += v * adv[n];
            }
            vs += __shfl_xor(vs, 1); vd += __shfl_xor(vd, 1);
            vs += __shfl_xor(vs, 2); vd += __shfl_xor(vd, 2);
            vs += __shfl_xor(vs, 4); vd += __shfl_xor(vd, 4);
            vs += __shfl_xor(vs, 8); vd += __shfl_xor(vd, 8);
            if ((lane & 15) == 0) {
                a_s[grow * 4 + head] = vs;
                a_d[grow * 4 + head] = vd;
            }
        }
    }
}

// ---------------- per-dst-node softmax-aggregate (one wave per node), bf16 in/out ----------------
__global__ __launch_bounds__(256) void k_agg(const u16* __restrict__ Hbf, const float* __restrict__ a_s,
                                             const float* __restrict__ a_d, const int* __restrict__ indptr,
                                             const int* __restrict__ esrc, const float* __restrict__ bias,
                                             u16* __restrict__ outbf) {
    int wid = (blockIdx.x * 256 + threadIdx.x) >> 6;
    if (wid >= NN) return;
    int lane = threadIdx.x & 63;
    int head = lane >> 4;
    int beg = indptr[wid], end = indptr[wid + 1];
    float ad = a_d[wid * 4 + head];

    float mx = -1e30f;
    int e = beg;
    for (; e + 2 <= end; e += 2) {
        int s0 = esrc[e], s1 = esrc[e + 1];
        float el0 = a_s[s0 * 4 + head] + ad;
        float el1 = a_s[s1 * 4 + head] + ad;
        el0 = el0 > 0.f ? el0 : 0.2f * el0;
        el1 = el1 > 0.f ? el1 : 0.2f * el1;
        mx = fmaxf(mx, fmaxf(el0, el1));
    }
    if (e < end) {
        int s0 = esrc[e];
        float el0 = a_s[s0 * 4 + head] + ad;
        el0 = el0 > 0.f ? el0 : 0.2f * el0;
        mx = fmaxf(mx, el0);
    }

    float ax = 0.f, ay = 0.f, az = 0.f, aw = 0.f, ssum = 0.f;
    e = beg;
    for (; e + 2 <= end; e += 2) {
        int s0 = esrc[e], s1 = esrc[e + 1];
        float el0 = a_s[s0 * 4 + head] + ad;
        float el1 = a_s[s1 * 4 + head] + ad;
        el0 = el0 > 0.f ? el0 : 0.2f * el0;
        el1 = el1 > 0.f ? el1 : 0.2f * el1;
        float p0 = __expf(el0 - mx), p1 = __expf(el1 - mx);
        ssum += p0 + p1;
        const ushort4 h0 = *reinterpret_cast<const ushort4*>(Hbf + (size_t)s0 * 256 + lane * 4);
        const ushort4 h1 = *reinterpret_cast<const ushort4*>(Hbf + (size_t)s1 * 256 + lane * 4);
        ax += p0 * bf2f(h0.x) + p1 * bf2f(h1.x);
        ay += p0 * bf2f(h0.y) + p1 * bf2f(h1.y);
        az += p0 * bf2f(h0.z) + p1 * bf2f(h1.z);
        aw += p0 * bf2f(h0.w) + p1 * bf2f(h1.w);
    }
    if (e < end) {
        int s0 = esrc[e];
        float el0 = a_s[s0 * 4 + head] + ad;
        el0 = el0 > 0.f ? el0 : 0.2f * el0;
        float p0 = __expf(el0 - mx);
        ssum += p0;
        const ushort4 h0 = *reinterpret_cast<const ushort4*>(Hbf + (size_t)s0 * 256 + lane * 4);
        ax += p0 * bf2f(h0.x);
        ay += p0 * bf2f(h0.y);
        az += p0 * bf2f(h0.z);
        aw += p0 * bf2f(h0.w);
    }

    float inv = 1.0f / ssum;
    const float4 bv = *reinterpret_cast<const float4*>(bias + lane * 4);
    ushort4 ob;
    ob.x = f2bf(fmaxf(ax * inv + bv.x, 0.f));
    ob.y = f2bf(fmaxf(ay * inv + bv.y, 0.f));
    ob.z = f2bf(fmaxf(az * inv + bv.z, 0.f));
    ob.w = f2bf(fmaxf(aw * inv + bv.w, 0.f));
    *reinterpret_cast<ushort4*>(outbf + (size_t)wid * 256 + lane * 4) = ob;
}

// ---------------- pooling, f32 input (n0, width 64) ----------------
__global__ __launch_bounds__(256) void k_pool_f32(const float* __restrict__ x, const int* __restrict__ batch,
                                                  int* __restrict__ gbuf, int off) {
    const int width = 64, S = 4;
    int c = threadIdx.x & 63;
    int sub = threadIdx.x >> 6;
    int base = blockIdx.x * 128;
    int end = min(base + 128, NN);
    float mx = 0.f;
    int curg = -1;
    for (int n = base + sub; n < end; n += S) {
        int g = batch[n];
        float v = x[(size_t)n * width + c];
        if (g != curg) {
            if (curg >= 0) atomicMax(&gbuf[curg * GCOLS + off + c], __float_as_int(mx));
            mx = 0.f; curg = g;
        }
        mx = fmaxf(mx, v);
    }
    if (curg >= 0) atomicMax(&gbuf[curg * GCOLS + off + c], __float_as_int(mx));
}

// ---------------- pooling, bf16 input (layers, width 256) ----------------
__global__ __launch_bounds__(256) void k_pool_bf(const u16* __restrict__ x, const int* __restrict__ batch,
                                                 int* __restrict__ gbuf, int off) {
    int c = threadIdx.x;
    int base = blockIdx.x * 128;
    int end = min(base + 128, NN);
    float mx = 0.f;
    int curg = -1;
    for (int n = base; n < end; ++n) {
        int g = batch[n];
        float v = bf2f(x[(size_t)n * 256 + c]);
        if (g != curg) {
            if (curg >= 0) atomicMax(&gbuf[curg * GCOLS + off + c], __float_as_int(mx));
            mx = 0.f; curg = g;
        }
        mx = fmaxf(mx, v);
    }
    if (curg >= 0) atomicMax(&gbuf[curg * GCOLS + off + c], __float_as_int(mx));
}

// ---------------- small dense layers ----------------
__global__ __launch_bounds__(256) void k_latent(const float* __restrict__ g, const float* __restrict__ W,
                                                const float* __restrict__ b, float* __restrict__ out) {
    int gi = blockIdx.x, j = threadIdx.x;
    float acc = b[j];
    const float* row = g + gi * GCOLS;
    for (int k = 0; k < GCOLS; ++k) acc += row[k] * W[k * 256 + j];
    out[gi * 256 + j] = acc;
}

__global__ __launch_bounds__(256) void k_proj(const float* __restrict__ x, const float* __restrict__ W,
                                              const float* __restrict__ b, float* __restrict__ out) {
    int gi = blockIdx.x, j = threadIdx.x;
    float acc = b[j];
    const float* row = x + gi * 256;
    for (int k = 0; k < 256; ++k) acc += row[k] * W[k * 256 + j];
    out[gi * 256 + j] = acc;
}

extern "C" void kernel_launch(void* const* d_in, const int* in_sizes, int n_in,
                              void* d_out, int out_size, void* d_ws, size_t ws_size,
                              hipStream_t stream) {
    const float* bf   = (const float*)d_in[0];
    const int*   ei   = (const int*)d_in[1];
    const int*   batch= (const int*)d_in[2];
    const float* bf_W = (const float*)d_in[3];
    const float* bf_b = (const float*)d_in[4];
    const float* W1   = (const float*)d_in[5];
    const float* as1  = (const float*)d_in[6];
    const float* ad1  = (const float*)d_in[7];
    const float* b1   = (const float*)d_in[8];
    const float* W2   = (const float*)d_in[9];
    const float* as2  = (const float*)d_in[10];
    const float* ad2  = (const float*)d_in[11];
    const float* b2   = (const float*)d_in[12];
    const float* W3   = (const float*)d_in[13];
    const float* as3  = (const float*)d_in[14];
    const float* ad3  = (const float*)d_in[15];
    const float* b3   = (const float*)d_in[16];
    const float* aggW = (const float*)d_in[17];
    const float* aggb = (const float*)d_in[18];
    const float* muW  = (const float*)d_in[19];
    const float* mub  = (const float*)d_in[20];
    const float* varW = (const float*)d_in[21];
    const float* varb = (const float*)d_in[22];
    float* out = (float*)d_out;

    size_t off = 0;
    auto alloc = [&](size_t bytes) -> char* {
        char* p = (char*)d_ws + off;
        off += (bytes + 255) & ~(size_t)255;
        return p;
    };
    u16*   Hbf     = (u16*)alloc((size_t)NPAD * 256 * 2);     // gemm out (bf16)
    float* n0f     = (float*)alloc((size_t)NN * 64 * 4);      // n0 f32 (exact pooling)
    u16*   n0bf    = (u16*)alloc((size_t)NPAD * 64 * 2);      // n0 bf16 (gemm1 in)
    u16*   nbf     = (u16*)alloc((size_t)NPAD * 256 * 2);     // layer activations bf16
    float* a_s     = (float*)alloc((size_t)NPAD * 4 * 4);
    float* a_d     = (float*)alloc((size_t)NPAD * 4 * 4);
    int*   counts  = (int*)alloc((size_t)NN * 4);
    int*   scanned = (int*)alloc((size_t)NN * 4);
    int*   bsums   = (int*)alloc(256 * 4);
    int*   indptr  = (int*)alloc((size_t)(NN + 1) * 4);
    int*   fill    = (int*)alloc((size_t)NN * 4);
    int*   esrc    = (int*)alloc((size_t)ETOT * 4);
    int*   gbuf    = (int*)alloc((size_t)GG * GCOLS * 4);
    float* latent  = (float*)alloc((size_t)GG * 256 * 4);
    u16*   Wt1     = (u16*)alloc((size_t)256 * 64 * 2);
    u16*   Wt2     = (u16*)alloc((size_t)256 * 256 * 2);
    u16*   Wt3     = (u16*)alloc((size_t)256 * 256 * 2);

    hipMemsetAsync(counts, 0, (size_t)NN * 4, stream);
    hipMemsetAsync(fill, 0, (size_t)NN * 4, stream);
    hipMemsetAsync(gbuf, 0, (size_t)GG * GCOLS * 4, stream);
    // zero bf16 pad rows (read by gemm staging)
    hipMemsetAsync(n0bf + (size_t)NN * 64, 0, (size_t)(NPAD - NN) * 64 * 2, stream);
    hipMemsetAsync(nbf + (size_t)NN * 256, 0, (size_t)(NPAD - NN) * 256 * 2, stream);

    // weight transposes
    k_wt<<<(256 * 64 + 255) / 256, 256, 0, stream>>>(W1, Wt1, 64);
    k_wt<<<(256 * 256 + 255) / 256, 256, 0, stream>>>(W2, Wt2, 256);
    k_wt<<<(256 * 256 + 255) / 256, 256, 0, stream>>>(W3, Wt3, 256);

    // n0
    k_n0<<<(NN * 64 + 255) / 256, 256, 0, stream>>>(bf, bf_W, bf_b, n0f, n0bf);

    // CSR
    const int EB = (ETOT + 255) / 256;
    const int NB = (NN + 255) / 256;
    k_count<<<EB, 256, 0, stream>>>(ei, counts);
    k_scan_block<<<NB, 256, 0, stream>>>(counts, scanned, bsums, NN);
    k_scan_sums<<<1, 256, 0, stream>>>(bsums, NB);
    k_scan_add<<<NB, 256, 0, stream>>>(scanned, bsums, indptr, NN, ETOT);
    k_fill<<<EB, 256, 0, stream>>>(ei, indptr, fill, esrc);

    const int PB = (NN + 127) / 128;  // 391
    k_pool_f32<<<PB, 256, 0, stream>>>(n0f, batch, gbuf, 0);

    dim3 ggrid(NPAD / BM, 256 / BN);  // (391, 2)
    // ---- layer 1 (K=64) ----
    k_gemm_mfma<<<ggrid, 256, 0, stream>>>(n0bf, Wt1, as1, ad1, Hbf, a_s, a_d, 64);
    k_agg<<<(NN + 3) / 4, 256, 0, stream>>>(Hbf, a_s, a_d, indptr, esrc, b1, nbf);
    k_pool_bf<<<PB, 256, 0, stream>>>(nbf, batch, gbuf, 64);

    // ---- layer 2 (K=256) ----
    k_gemm_mfma<<<ggrid, 256, 0, stream>>>(nbf, Wt2, as2, ad2, Hbf, a_s, a_d, 256);
    k_agg<<<(NN + 3) / 4, 256, 0, stream>>>(Hbf, a_s, a_d, indptr, esrc, b2, nbf);
    k_pool_bf<<<PB, 256, 0, stream>>>(nbf, batch, gbuf, 320);

    // ---- layer 3 (K=256) ----
    k_gemm_mfma<<<ggrid, 256, 0, stream>>>(nbf, Wt3, as3, ad3, Hbf, a_s, a_d, 256);
    k_agg<<<(NN + 3) / 4, 256, 0, stream>>>(Hbf, a_s, a_d, indptr, esrc, b3, nbf);
    k_pool_bf<<<PB, 256, 0, stream>>>(nbf, batch, gbuf, 576);

    // ---- head ----
    k_latent<<<GG, 256, 0, stream>>>((const float*)gbuf, aggW, aggb, latent);
    k_proj<<<GG, 256, 0, stream>>>(latent, muW, mub, out);
    k_proj<<<GG, 256, 0, stream>>>(latent, varW, varb, out + GG * 256);
}

// Round 4
// 370.936 us; speedup vs baseline: 4.7228x; 1.1584x over previous
//
#include <hip/hip_runtime.h>
#include <hip/hip_bf16.h>

#define NN 50000
#define NPAD 50048              // 391 * 128
#define EE 300000
#define ETOT (EE + NN)          // 350000 edges incl self-loops
#define GG 64
#define GCOLS 832               // 64 + 3*256
#define LATD 256
#define BM 128
#define BN 128

typedef unsigned short u16;
typedef short s16x8 __attribute__((ext_vector_type(8)));
typedef float f32x4 __attribute__((ext_vector_type(4)));

__device__ __forceinline__ u16 f2bf(float f) {
    union { float f; unsigned u; } v; v.f = f;
    unsigned r = v.u + 0x7FFFu + ((v.u >> 16) & 1u);
    return (u16)(r >> 16);
}
__device__ __forceinline__ float bf2f(u16 u) {
    union { unsigned u; float f; } v; v.u = ((unsigned)u) << 16;
    return v.f;
}

// ---------------- all three weight transposes in one launch ----------------
__global__ __launch_bounds__(256) void k_wt_all(const float* __restrict__ W1, const float* __restrict__ W2,
                                                const float* __restrict__ W3, u16* __restrict__ Wt1,
                                                u16* __restrict__ Wt2, u16* __restrict__ Wt3) {
    int idx = blockIdx.x * 256 + threadIdx.x;
    if (idx < 16384) {
        int n = idx >> 6, k = idx & 63;
        Wt1[idx] = f2bf(W1[k * 256 + n]);
    } else if (idx < 81920) {
        int t = idx - 16384; int n = t >> 8, k = t & 255;
        Wt2[t] = f2bf(W2[k * 256 + n]);
    } else if (idx < 147456) {
        int t = idx - 81920; int n = t >> 8, k = t & 255;
        Wt3[t] = f2bf(W3[k * 256 + n]);
    }
}

// ---------------- fused n0 = relu(bf @ bf_W + bf_b) + segment-max pool ----------------
// block = 128 consecutive nodes (sorted by batch), 256 thr: c = tid&63, node-slot = tid>>6 (stride 4)
__global__ __launch_bounds__(256) void k_n0_pool(const float* __restrict__ bf,
                                                 const float* __restrict__ Wb,
                                                 const float* __restrict__ bb,
                                                 const int* __restrict__ batch,
                                                 u16* __restrict__ outbf,
                                                 int* __restrict__ gbuf) {
    int c = threadIdx.x & 63;
    int sub = threadIdx.x >> 6;
    int base = blockIdx.x * 128;
    int end = min(base + 128, NN);
    float w0 = Wb[0 * 64 + c], w1 = Wb[1 * 64 + c], w2 = Wb[2 * 64 + c],
          w3 = Wb[3 * 64 + c], w4 = Wb[4 * 64 + c], b = bb[c];
    float mx = 0.f;
    int curg = -1;
    for (int n = base + sub; n < end; n += 4) {
        const float* r = bf + (size_t)n * 5;
        float v = b + r[0] * w0 + r[1] * w1 + r[2] * w2 + r[3] * w3 + r[4] * w4;
        v = fmaxf(v, 0.f);
        outbf[(size_t)n * 64 + c] = f2bf(v);
        int g = batch[n];
        if (g != curg) {
            if (curg >= 0) atomicMax(&gbuf[curg * GCOLS + c], __float_as_int(mx));
            mx = 0.f; curg = g;
        }
        mx = fmaxf(mx, v);
    }
    if (curg >= 0) atomicMax(&gbuf[curg * GCOLS + c], __float_as_int(mx));
}

// ---------------- CSR build ----------------
__global__ __launch_bounds__(256) void k_count(const int* __restrict__ ei, int* __restrict__ counts) {
    int e = blockIdx.x * 256 + threadIdx.x;
    if (e >= ETOT) return;
    int d = (e < EE) ? ei[EE + e] : (e - EE);
    atomicAdd(&counts[d], 1);
}

__global__ __launch_bounds__(256) void k_scan_block(const int* __restrict__ counts, int* __restrict__ scanned,
                                                    int* __restrict__ bsums, int n) {
    __shared__ int sh[256];
    int i = blockIdx.x * 256 + threadIdx.x;
    int v = (i < n) ? counts[i] : 0;
    sh[threadIdx.x] = v; __syncthreads();
    for (int d = 1; d < 256; d <<= 1) {
        int t = (threadIdx.x >= d) ? sh[threadIdx.x - d] : 0;
        __syncthreads();
        sh[threadIdx.x] += t;
        __syncthreads();
    }
    if (i < n) scanned[i] = sh[threadIdx.x] - v;
    if (threadIdx.x == 255) bsums[blockIdx.x] = sh[255];
}

__global__ __launch_bounds__(256) void k_scan_sums(int* __restrict__ bsums, int nb) {
    __shared__ int sh[256];
    int v = (threadIdx.x < nb) ? bsums[threadIdx.x] : 0;
    sh[threadIdx.x] = v; __syncthreads();
    for (int d = 1; d < 256; d <<= 1) {
        int t = (threadIdx.x >= d) ? sh[threadIdx.x - d] : 0;
        __syncthreads();
        sh[threadIdx.x] += t;
        __syncthreads();
    }
    if (threadIdx.x < nb) bsums[threadIdx.x] = sh[threadIdx.x] - v;
}

__global__ __launch_bounds__(256) void k_scan_add(const int* __restrict__ scanned, const int* __restrict__ boffs,
                                                  int* __restrict__ indptr, int n, int total) {
    int i = blockIdx.x * 256 + threadIdx.x;
    if (i < n) indptr[i] = scanned[i] + boffs[i >> 8];
    if (i == 0) indptr[n] = total;
}

__global__ __launch_bounds__(256) void k_fill(const int* __restrict__ ei, const int* __restrict__ indptr,
                                              int* __restrict__ fill, int* __restrict__ esrc) {
    int e = blockIdx.x * 256 + threadIdx.x;
    if (e >= ETOT) return;
    int s, d;
    if (e < EE) { s = ei[e]; d = ei[EE + e]; } else { s = d = e - EE; }
    int pos = atomicAdd(&fill[d], 1);
    esrc[indptr[d] + pos] = s;
}

// ---------------- bf16 MFMA GEMM + fused a_s/a_d epilogue ----------------
__global__ __launch_bounds__(256) void k_gemm_mfma(const u16* __restrict__ A,
                                                   const u16* __restrict__ Bt,
                                                   const float* __restrict__ att_s,
                                                   const float* __restrict__ att_d,
                                                   u16* __restrict__ Hbf,
                                                   float* __restrict__ a_s,
                                                   float* __restrict__ a_d,
                                                   int K) {
    __shared__ __align__(16) u16 As[128 * 64];
    __shared__ __align__(16) u16 Bs[128 * 64];
    const int tid = threadIdx.x;
    const int lane = tid & 63;
    const int w = tid >> 6;
    const int wr = w >> 1, wc = w & 1;
    const int row0 = blockIdx.x * BM;
    const int col0 = blockIdx.y * BN;

    f32x4 acc[4][4] = {};

    for (int kt = 0; kt < K; kt += 64) {
#pragma unroll
        for (int i = 0; i < 4; ++i) {
            int u = i * 256 + tid;
            int r = u >> 3, c16 = u & 7;
            int sc = ((c16 ^ (r & 7)) << 3);
            const u16* ga = A + (size_t)(row0 + r) * K + kt + sc;
            u16* la = &As[(size_t)(i * 256 + (w << 6)) * 8];
            __builtin_amdgcn_global_load_lds((const __attribute__((address_space(1))) void*)ga,
                                             (__attribute__((address_space(3))) void*)la, 16, 0, 0);
        }
#pragma unroll
        for (int i = 0; i < 4; ++i) {
            int u = i * 256 + tid;
            int r = u >> 3, c16 = u & 7;
            int sc = ((c16 ^ (r & 7)) << 3);
            const u16* gb = Bt + (size_t)(col0 + r) * K + kt + sc;
            u16* lb = &Bs[(size_t)(i * 256 + (w << 6)) * 8];
            __builtin_amdgcn_global_load_lds((const __attribute__((address_space(1))) void*)gb,
                                             (__attribute__((address_space(3))) void*)lb, 16, 0, 0);
        }
        __syncthreads();
#pragma unroll
        for (int ks = 0; ks < 2; ++ks) {
            s16x8 af[4], bfr[4];
#pragma unroll
            for (int m = 0; m < 4; ++m) {
                int ra = wr * 64 + m * 16 + (lane & 15);
                int c16 = ks * 4 + (lane >> 4);
                int off = ra * 64 + ((c16 ^ (ra & 7)) << 3);
                af[m] = *reinterpret_cast<const s16x8*>(&As[off]);
            }
#pragma unroll
            for (int n = 0; n < 4; ++n) {
                int rb = wc * 64 + n * 16 + (lane & 15);
                int c16 = ks * 4 + (lane >> 4);
                int off = rb * 64 + ((c16 ^ (rb & 7)) << 3);
                bfr[n] = *reinterpret_cast<const s16x8*>(&Bs[off]);
            }
#pragma unroll
            for (int m = 0; m < 4; ++m)
#pragma unroll
                for (int n = 0; n < 4; ++n)
                    acc[m][n] = __builtin_amdgcn_mfma_f32_16x16x32_bf16(af[m], bfr[n], acc[m][n], 0, 0, 0);
        }
        __syncthreads();
    }

    const int head = (blockIdx.y << 1) + wc;
    float asv[4], adv[4];
#pragma unroll
    for (int n = 0; n < 4; ++n) {
        asv[n] = att_s[head * 64 + n * 16 + (lane & 15)];
        adv[n] = att_d[head * 64 + n * 16 + (lane & 15)];
    }
#pragma unroll
    for (int m = 0; m < 4; ++m) {
        int growb = row0 + wr * 64 + m * 16 + (lane >> 4) * 4;
#pragma unroll
        for (int j = 0; j < 4; ++j) {
            int grow = growb + j;
            u16* orow = Hbf + (size_t)grow * 256 + col0 + wc * 64 + (lane & 15);
            float vs = 0.f, vd = 0.f;
#pragma unroll
            for (int n = 0; n < 4; ++n) {
                float v = acc[m][n][j];
                orow[n * 16] = f2bf(v);
                vs += v * asv[n];
                vd += v * adv[n];
            }
            vs += __shfl_xor(vs, 1); vd += __shfl_xor(vd, 1);
            vs += __shfl_xor(vs, 2); vd += __shfl_xor(vd, 2);
            vs += __shfl_xor(vs, 4); vd += __shfl_xor(vd, 4);
            vs += __shfl_xor(vs, 8); vd += __shfl_xor(vd, 8);
            if ((lane & 15) == 0) {
                a_s[grow * 4 + head] = vs;
                a_d[grow * 4 + head] = vd;
            }
        }
    }
}

// ---------------- single-pass online-softmax aggregate (one wave per node) ----------------
__global__ __launch_bounds__(256) void k_agg(const u16* __restrict__ Hbf, const float* __restrict__ a_s,
                                             const float* __restrict__ a_d, const int* __restrict__ indptr,
                                             const int* __restrict__ esrc, const float* __restrict__ bias,
                                             u16* __restrict__ outbf) {
    int wid = (blockIdx.x * 256 + threadIdx.x) >> 6;
    if (wid >= NN) return;
    int lane = threadIdx.x & 63;
    int head = lane >> 4;
    int beg = indptr[wid], end = indptr[wid + 1];
    float ad = a_d[wid * 4 + head];

    float mx = -3.0e38f;
    float ssum = 0.f;
    float ax = 0.f, ay = 0.f, az = 0.f, aw = 0.f;
    int e = beg;
    for (; e + 2 <= end; e += 2) {
        int s0 = esrc[e], s1 = esrc[e + 1];
        float el0 = a_s[s0 * 4 + head] + ad;
        float el1 = a_s[s1 * 4 + head] + ad;
        el0 = fmaxf(el0, 0.2f * el0);
        el1 = fmaxf(el1, 0.2f * el1);
        float nm = fmaxf(mx, fmaxf(el0, el1));
        if (__any(nm > mx)) {
            float corr = __expf(mx - nm);   // lanes with no new max: corr = exp(0) = 1
            ssum *= corr; ax *= corr; ay *= corr; az *= corr; aw *= corr;
            mx = nm;
        }
        float p0 = __expf(el0 - mx), p1 = __expf(el1 - mx);
        ssum += p0 + p1;
        const ushort4 h0 = *reinterpret_cast<const ushort4*>(Hbf + (size_t)s0 * 256 + lane * 4);
        const ushort4 h1 = *reinterpret_cast<const ushort4*>(Hbf + (size_t)s1 * 256 + lane * 4);
        ax += p0 * bf2f(h0.x) + p1 * bf2f(h1.x);
        ay += p0 * bf2f(h0.y) + p1 * bf2f(h1.y);
        az += p0 * bf2f(h0.z) + p1 * bf2f(h1.z);
        aw += p0 * bf2f(h0.w) + p1 * bf2f(h1.w);
    }
    if (e < end) {
        int s0 = esrc[e];
        float el0 = a_s[s0 * 4 + head] + ad;
        el0 = fmaxf(el0, 0.2f * el0);
        float nm = fmaxf(mx, el0);
        if (__any(nm > mx)) {
            float corr = __expf(mx - nm);
            ssum *= corr; ax *= corr; ay *= corr; az *= corr; aw *= corr;
            mx = nm;
        }
        float p0 = __expf(el0 - mx);
        ssum += p0;
        const ushort4 h0 = *reinterpret_cast<const ushort4*>(Hbf + (size_t)s0 * 256 + lane * 4);
        ax += p0 * bf2f(h0.x);
        ay += p0 * bf2f(h0.y);
        az += p0 * bf2f(h0.z);
        aw += p0 * bf2f(h0.w);
    }

    float inv = 1.0f / ssum;
    const float4 bv = *reinterpret_cast<const float4*>(bias + lane * 4);
    ushort4 ob;
    ob.x = f2bf(fmaxf(ax * inv + bv.x, 0.f));
    ob.y = f2bf(fmaxf(ay * inv + bv.y, 0.f));
    ob.z = f2bf(fmaxf(az * inv + bv.z, 0.f));
    ob.w = f2bf(fmaxf(aw * inv + bv.w, 0.f));
    *reinterpret_cast<ushort4*>(outbf + (size_t)wid * 256 + lane * 4) = ob;
}

// ---------------- pooling, bf16 input (width 256), ushort4-vectorized ----------------
// block = 64 consecutive nodes, 4 node-slots x 64 lanes x 4 channels
__global__ __launch_bounds__(256) void k_pool_bf(const u16* __restrict__ x, const int* __restrict__ batch,
                                                 int* __restrict__ gbuf, int off) {
    int sub = threadIdx.x >> 6;
    int c4 = (threadIdx.x & 63) * 4;
    int base = blockIdx.x * 64;
    int end = min(base + 64, NN);
    float m0 = 0.f, m1 = 0.f, m2 = 0.f, m3 = 0.f;
    int curg = -1;
    for (int n = base + sub; n < end; n += 4) {
        int g = batch[n];
        const ushort4 hv = *reinterpret_cast<const ushort4*>(x + (size_t)n * 256 + c4);
        if (g != curg) {
            if (curg >= 0) {
                int* cell = &gbuf[curg * GCOLS + off + c4];
                atomicMax(cell,     __float_as_int(m0));
                atomicMax(cell + 1, __float_as_int(m1));
                atomicMax(cell + 2, __float_as_int(m2));
                atomicMax(cell + 3, __float_as_int(m3));
            }
            m0 = m1 = m2 = m3 = 0.f; curg = g;
        }
        m0 = fmaxf(m0, bf2f(hv.x));
        m1 = fmaxf(m1, bf2f(hv.y));
        m2 = fmaxf(m2, bf2f(hv.z));
        m3 = fmaxf(m3, bf2f(hv.w));
    }
    if (curg >= 0) {
        int* cell = &gbuf[curg * GCOLS + off + c4];
        atomicMax(cell,     __float_as_int(m0));
        atomicMax(cell + 1, __float_as_int(m1));
        atomicMax(cell + 2, __float_as_int(m2));
        atomicMax(cell + 3, __float_as_int(m3));
    }
}

// ---------------- fused head: latent -> mu & log_var, one block per graph ----------------
__global__ __launch_bounds__(256) void k_head(const int* __restrict__ gbuf,
                                              const float* __restrict__ aggW, const float* __restrict__ aggb,
                                              const float* __restrict__ muW, const float* __restrict__ mub,
                                              const float* __restrict__ varW, const float* __restrict__ varb,
                                              float* __restrict__ out) {
    __shared__ float lat[LATD];
    int gi = blockIdx.x, j = threadIdx.x;
    const float* g = (const float*)gbuf + (size_t)gi * GCOLS;
    float acc = aggb[j];
    for (int k = 0; k < GCOLS; ++k) acc += g[k] * aggW[k * 256 + j];
    lat[j] = acc;
    __syncthreads();
    float am = mub[j], av = varb[j];
    for (int k = 0; k < 256; ++k) {
        float l = lat[k];
        am += l * muW[k * 256 + j];
        av += l * varW[k * 256 + j];
    }
    out[(size_t)gi * 256 + j] = am;
    out[(size_t)GG * 256 + (size_t)gi * 256 + j] = av;
}

extern "C" void kernel_launch(void* const* d_in, const int* in_sizes, int n_in,
                              void* d_out, int out_size, void* d_ws, size_t ws_size,
                              hipStream_t stream) {
    const float* bf   = (const float*)d_in[0];
    const int*   ei   = (const int*)d_in[1];
    const int*   batch= (const int*)d_in[2];
    const float* bf_W = (const float*)d_in[3];
    const float* bf_b = (const float*)d_in[4];
    const float* W1   = (const float*)d_in[5];
    const float* as1  = (const float*)d_in[6];
    const float* ad1  = (const float*)d_in[7];
    const float* b1   = (const float*)d_in[8];
    const float* W2   = (const float*)d_in[9];
    const float* as2  = (const float*)d_in[10];
    const float* ad2  = (const float*)d_in[11];
    const float* b2   = (const float*)d_in[12];
    const float* W3   = (const float*)d_in[13];
    const float* as3  = (const float*)d_in[14];
    const float* ad3  = (const float*)d_in[15];
    const float* b3   = (const float*)d_in[16];
    const float* aggW = (const float*)d_in[17];
    const float* aggb = (const float*)d_in[18];
    const float* muW  = (const float*)d_in[19];
    const float* mub  = (const float*)d_in[20];
    const float* varW = (const float*)d_in[21];
    const float* varb = (const float*)d_in[22];
    float* out = (float*)d_out;

    size_t off = 0;
    auto alloc = [&](size_t bytes) -> char* {
        char* p = (char*)d_ws + off;
        off += (bytes + 255) & ~(size_t)255;
        return p;
    };
    u16*   Hbf     = (u16*)alloc((size_t)NPAD * 256 * 2);
    u16*   n0bf    = (u16*)alloc((size_t)NPAD * 64 * 2);
    u16*   nbf     = (u16*)alloc((size_t)NPAD * 256 * 2);
    float* a_s     = (float*)alloc((size_t)NPAD * 4 * 4);
    float* a_d     = (float*)alloc((size_t)NPAD * 4 * 4);
    int*   counts  = (int*)alloc((size_t)2 * NN * 4);   // counts + fill adjacent, one memset
    int*   fill    = counts + NN;
    int*   scanned = (int*)alloc((size_t)NN * 4);
    int*   bsums   = (int*)alloc(256 * 4);
    int*   indptr  = (int*)alloc((size_t)(NN + 1) * 4);
    int*   esrc    = (int*)alloc((size_t)ETOT * 4);
    int*   gbuf    = (int*)alloc((size_t)GG * GCOLS * 4);
    u16*   Wt1     = (u16*)alloc((size_t)256 * 64 * 2);
    u16*   Wt2     = (u16*)alloc((size_t)256 * 256 * 2);
    u16*   Wt3     = (u16*)alloc((size_t)256 * 256 * 2);

    hipMemsetAsync(counts, 0, (size_t)2 * NN * 4, stream);
    hipMemsetAsync(gbuf, 0, (size_t)GG * GCOLS * 4, stream);
    hipMemsetAsync(n0bf + (size_t)NN * 64, 0, (size_t)(NPAD - NN) * 64 * 2, stream);
    hipMemsetAsync(nbf + (size_t)NN * 256, 0, (size_t)(NPAD - NN) * 256 * 2, stream);

    k_wt_all<<<576, 256, 0, stream>>>(W1, W2, W3, Wt1, Wt2, Wt3);

    const int PB128 = (NN + 127) / 128;  // 391
    k_n0_pool<<<PB128, 256, 0, stream>>>(bf, bf_W, bf_b, batch, n0bf, gbuf);

    const int EB = (ETOT + 255) / 256;
    const int NB = (NN + 255) / 256;
    k_count<<<EB, 256, 0, stream>>>(ei, counts);
    k_scan_block<<<NB, 256, 0, stream>>>(counts, scanned, bsums, NN);
    k_scan_sums<<<1, 256, 0, stream>>>(bsums, NB);
    k_scan_add<<<NB, 256, 0, stream>>>(scanned, bsums, indptr, NN, ETOT);
    k_fill<<<EB, 256, 0, stream>>>(ei, indptr, fill, esrc);

    const int PB64 = (NN + 63) / 64;     // 782
    dim3 ggrid(NPAD / BM, 256 / BN);     // (391, 2)

    // ---- layer 1 (K=64) ----
    k_gemm_mfma<<<ggrid, 256, 0, stream>>>(n0bf, Wt1, as1, ad1, Hbf, a_s, a_d, 64);
    k_agg<<<(NN + 3) / 4, 256, 0, stream>>>(Hbf, a_s, a_d, indptr, esrc, b1, nbf);
    k_pool_bf<<<PB64, 256, 0, stream>>>(nbf, batch, gbuf, 64);

    // ---- layer 2 (K=256) ----
    k_gemm_mfma<<<ggrid, 256, 0, stream>>>(nbf, Wt2, as2, ad2, Hbf, a_s, a_d, 256);
    k_agg<<<(NN + 3) / 4, 256, 0, stream>>>(Hbf, a_s, a_d, indptr, esrc, b2, nbf);
    k_pool_bf<<<PB64, 256, 0, stream>>>(nbf, batch, gbuf, 320);

    // ---- layer 3 (K=256) ----
    k_gemm_mfma<<<ggrid, 256, 0, stream>>>(nbf, Wt3, as3, ad3, Hbf, a_s, a_d, 256);
    k_agg<<<(NN + 3) / 4, 256, 0, stream>>>(Hbf, a_s, a_d, indptr, esrc, b3, nbf);
    k_pool_bf<<<PB64, 256, 0, stream>>>(nbf, batch, gbuf, 576);

    // ---- head (single kernel) ----
    k_head<<<GG, 256, 0, stream>>>(gbuf, aggW, aggb, muW, mub, varW, varb, out);
}

// Round 5
// 275.853 us; speedup vs baseline: 6.3507x; 1.3447x over previous
//
#include <hip/hip_runtime.h>
#include <hip/hip_bf16.h>

#define NN 50000
#define NPAD 50048              // 391 * 128
#define EE 300000
#define ETOT (EE + NN)          // 350000 edges incl self-loops
#define GG 64
#define GCOLS 832               // 64 + 3*256
#define LATD 256
#define BM 128
#define BN 128
#define NB_SCAN 196             // (NN+255)/256
#define LOG2E 1.4426950408889634f

typedef unsigned short u16;
typedef short s16x8 __attribute__((ext_vector_type(8)));
typedef float f32x4 __attribute__((ext_vector_type(4)));

__device__ __forceinline__ u16 f2bf(float f) {
    union { float f; unsigned u; } v; v.f = f;
    unsigned r = v.u + 0x7FFFu + ((v.u >> 16) & 1u);
    return (u16)(r >> 16);
}
__device__ __forceinline__ float bf2f(u16 u) {
    union { unsigned u; float f; } v; v.u = ((unsigned)u) << 16;
    return v.f;
}

// ---------------- prep: weight transposes | n0+pool | edge count | pad zero ----------------
__global__ __launch_bounds__(256) void k_prep(const float* __restrict__ W1, const float* __restrict__ W2,
                                              const float* __restrict__ W3, u16* __restrict__ Wt1,
                                              u16* __restrict__ Wt2, u16* __restrict__ Wt3,
                                              const float* __restrict__ bf, const float* __restrict__ Wb,
                                              const float* __restrict__ bb, const int* __restrict__ batch,
                                              u16* __restrict__ n0bf, int* __restrict__ gbuf,
                                              const int* __restrict__ ei, int* __restrict__ counts,
                                              u16* __restrict__ nbf) {
    int b = blockIdx.x;
    if (b < 576) {
        int idx = b * 256 + threadIdx.x;
        if (idx < 16384) {
            int n = idx >> 6, k = idx & 63;
            Wt1[idx] = f2bf(W1[k * 256 + n]);
        } else if (idx < 81920) {
            int t = idx - 16384; int n = t >> 8, k = t & 255;
            Wt2[t] = f2bf(W2[k * 256 + n]);
        } else {
            int t = idx - 81920; int n = t >> 8, k = t & 255;
            Wt3[t] = f2bf(W3[k * 256 + n]);
        }
    } else if (b < 967) {
        // n0 = relu(bf @ bf_W + bf_b) -> bf16, + fused segment-max pool (off 0)
        int c = threadIdx.x & 63;
        int sub = threadIdx.x >> 6;
        int base = (b - 576) * 128;
        int end = min(base + 128, NN);
        float w0 = Wb[c], w1 = Wb[64 + c], w2 = Wb[128 + c], w3 = Wb[192 + c], w4 = Wb[256 + c], bb_ = bb[c];
        float mx = 0.f;
        int curg = -1;
        for (int n = base + sub; n < end; n += 4) {
            const float* r = bf + (size_t)n * 5;
            float v = bb_ + r[0] * w0 + r[1] * w1 + r[2] * w2 + r[3] * w3 + r[4] * w4;
            v = fmaxf(v, 0.f);
            n0bf[(size_t)n * 64 + c] = f2bf(v);
            int g = batch[n];
            if (g != curg) {
                if (curg >= 0) atomicMax(&gbuf[curg * GCOLS + c], __float_as_int(mx));
                mx = 0.f; curg = g;
            }
            mx = fmaxf(mx, v);
        }
        if (curg >= 0) atomicMax(&gbuf[curg * GCOLS + c], __float_as_int(mx));
    } else if (b < 2335) {
        int e = (b - 967) * 256 + threadIdx.x;
        if (e < ETOT) {
            int d = (e < EE) ? ei[EE + e] : (e - EE);
            atomicAdd(&counts[d], 1);
        }
    } else {
        // zero pad rows of n0bf and nbf (read by GEMM staging)
        u16* p0 = n0bf + (size_t)NN * 64;
        for (int i = threadIdx.x; i < (NPAD - NN) * 64; i += 256) p0[i] = 0;
        u16* p1 = nbf + (size_t)NN * 256;
        for (int i = threadIdx.x; i < (NPAD - NN) * 256; i += 256) p1[i] = 0;
    }
}

// ---------------- CSR scan ----------------
__global__ __launch_bounds__(256) void k_scan_block(const int* __restrict__ counts, int* __restrict__ scanned,
                                                    int* __restrict__ bsums, int n) {
    __shared__ int sh[256];
    int i = blockIdx.x * 256 + threadIdx.x;
    int v = (i < n) ? counts[i] : 0;
    sh[threadIdx.x] = v; __syncthreads();
    for (int d = 1; d < 256; d <<= 1) {
        int t = (threadIdx.x >= d) ? sh[threadIdx.x - d] : 0;
        __syncthreads();
        sh[threadIdx.x] += t;
        __syncthreads();
    }
    if (i < n) scanned[i] = sh[threadIdx.x] - v;
    if (threadIdx.x == 255) bsums[blockIdx.x] = sh[255];
}

// fused: scan of bsums (redundant per block) + add + fill-zero
__global__ __launch_bounds__(256) void k_scan_add2(const int* __restrict__ scanned, const int* __restrict__ bsums,
                                                   int* __restrict__ indptr, int* __restrict__ fill) {
    __shared__ int sh[256];
    int t = threadIdx.x;
    int v = (t < NB_SCAN) ? bsums[t] : 0;
    sh[t] = v; __syncthreads();
    for (int d = 1; d < 256; d <<= 1) {
        int u = (t >= d) ? sh[t - d] : 0;
        __syncthreads();
        sh[t] += u;
        __syncthreads();
    }
    int bix = blockIdx.x;
    int boff = (bix == 0) ? 0 : sh[bix - 1];
    int i = bix * 256 + t;
    if (i < NN) { indptr[i] = scanned[i] + boff; fill[i] = 0; }
    if (i == 0) indptr[NN] = ETOT;
}

__global__ __launch_bounds__(256) void k_fill(const int* __restrict__ ei, const int* __restrict__ indptr,
                                              int* __restrict__ fill, int* __restrict__ esrc) {
    int e = blockIdx.x * 256 + threadIdx.x;
    if (e >= ETOT) return;
    int s, d;
    if (e < EE) { s = ei[e]; d = ei[EE + e]; } else { s = d = e - EE; }
    int pos = atomicAdd(&fill[d], 1);
    esrc[indptr[d] + pos] = s;
}

// ---------------- bf16 MFMA GEMM + fused a_s/a_d epilogue (scores pre-scaled by log2e) ----------------
__global__ __launch_bounds__(256) void k_gemm_mfma(const u16* __restrict__ A,
                                                   const u16* __restrict__ Bt,
                                                   const float* __restrict__ att_s,
                                                   const float* __restrict__ att_d,
                                                   u16* __restrict__ Hbf,
                                                   float* __restrict__ a_s,
                                                   float* __restrict__ a_d,
                                                   int K) {
    __shared__ __align__(16) u16 As[128 * 64];
    __shared__ __align__(16) u16 Bs[128 * 64];
    const int tid = threadIdx.x;
    const int lane = tid & 63;
    const int w = tid >> 6;
    const int wr = w >> 1, wc = w & 1;
    const int row0 = blockIdx.x * BM;
    const int col0 = blockIdx.y * BN;

    f32x4 acc[4][4] = {};

    for (int kt = 0; kt < K; kt += 64) {
#pragma unroll
        for (int i = 0; i < 4; ++i) {
            int u = i * 256 + tid;
            int r = u >> 3, c16 = u & 7;
            int sc = ((c16 ^ (r & 7)) << 3);
            const u16* ga = A + (size_t)(row0 + r) * K + kt + sc;
            u16* la = &As[(size_t)(i * 256 + (w << 6)) * 8];
            __builtin_amdgcn_global_load_lds((const __attribute__((address_space(1))) void*)ga,
                                             (__attribute__((address_space(3))) void*)la, 16, 0, 0);
        }
#pragma unroll
        for (int i = 0; i < 4; ++i) {
            int u = i * 256 + tid;
            int r = u >> 3, c16 = u & 7;
            int sc = ((c16 ^ (r & 7)) << 3);
            const u16* gb = Bt + (size_t)(col0 + r) * K + kt + sc;
            u16* lb = &Bs[(size_t)(i * 256 + (w << 6)) * 8];
            __builtin_amdgcn_global_load_lds((const __attribute__((address_space(1))) void*)gb,
                                             (__attribute__((address_space(3))) void*)lb, 16, 0, 0);
        }
        __syncthreads();
#pragma unroll
        for (int ks = 0; ks < 2; ++ks) {
            s16x8 af[4], bfr[4];
#pragma unroll
            for (int m = 0; m < 4; ++m) {
                int ra = wr * 64 + m * 16 + (lane & 15);
                int c16 = ks * 4 + (lane >> 4);
                int off = ra * 64 + ((c16 ^ (ra & 7)) << 3);
                af[m] = *reinterpret_cast<const s16x8*>(&As[off]);
            }
#pragma unroll
            for (int n = 0; n < 4; ++n) {
                int rb = wc * 64 + n * 16 + (lane & 15);
                int c16 = ks * 4 + (lane >> 4);
                int off = rb * 64 + ((c16 ^ (rb & 7)) << 3);
                bfr[n] = *reinterpret_cast<const s16x8*>(&Bs[off]);
            }
#pragma unroll
            for (int m = 0; m < 4; ++m)
#pragma unroll
                for (int n = 0; n < 4; ++n)
                    acc[m][n] = __builtin_amdgcn_mfma_f32_16x16x32_bf16(af[m], bfr[n], acc[m][n], 0, 0, 0);
        }
        __syncthreads();
    }

    const int head = (blockIdx.y << 1) + wc;
    float asv[4], adv[4];
#pragma unroll
    for (int n = 0; n < 4; ++n) {
        asv[n] = att_s[head * 64 + n * 16 + (lane & 15)] * LOG2E;
        adv[n] = att_d[head * 64 + n * 16 + (lane & 15)] * LOG2E;
    }
#pragma unroll
    for (int m = 0; m < 4; ++m) {
        int growb = row0 + wr * 64 + m * 16 + (lane >> 4) * 4;
#pragma unroll
        for (int j = 0; j < 4; ++j) {
            int grow = growb + j;
            u16* orow = Hbf + (size_t)grow * 256 + col0 + wc * 64 + (lane & 15);
            float vs = 0.f, vd = 0.f;
#pragma unroll
            for (int n = 0; n < 4; ++n) {
                float v = acc[m][n][j];
                orow[n * 16] = f2bf(v);
                vs += v * asv[n];
                vd += v * adv[n];
            }
            vs += __shfl_xor(vs, 1); vd += __shfl_xor(vd, 1);
            vs += __shfl_xor(vs, 2); vd += __shfl_xor(vd, 2);
            vs += __shfl_xor(vs, 4); vd += __shfl_xor(vd, 4);
            vs += __shfl_xor(vs, 8); vd += __shfl_xor(vd, 8);
            if ((lane & 15) == 0) {
                a_s[grow * 4 + head] = vs;
                a_d[grow * 4 + head] = vd;
            }
        }
    }
}

// ---------------- two-phase online-softmax aggregate + fused pool ----------------
// block = 1024 thr = 16 waves = 16 consecutive nodes (batch-sorted); LDS dedup pool table.
__global__ __launch_bounds__(1024) void k_agg(const u16* __restrict__ Hbf, const float* __restrict__ a_s,
                                              const float* __restrict__ a_d, const int* __restrict__ indptr,
                                              const int* __restrict__ esrc, const float* __restrict__ bias,
                                              const int* __restrict__ batch, u16* __restrict__ outbf,
                                              int* __restrict__ gbuf, int poolOff) {
    __shared__ int lpool[2][256];
    if (threadIdx.x < 512) lpool[threadIdx.x >> 8][threadIdx.x & 255] = 0;
    __syncthreads();

    const int nodeBase = blockIdx.x * 16;
    const int wv = threadIdx.x >> 6;
    const int wid = nodeBase + wv;
    const int lane = threadIdx.x & 63;
    const int h = lane >> 4;
    const int eidx = lane & 15;
    const bool active = wid < NN;

    if (active) {
        int beg = indptr[wid];
        int dcount = indptr[wid + 1] - beg;
        float ad = a_d[wid * 4 + h];
        float mx = -3.0e38f, ssum = 0.f;
        float ax = 0.f, ay = 0.f, az = 0.f, aw = 0.f;

        for (int cb = 0; cb < dcount; cb += 16) {
            int cnt = min(16, dcount - cb);
            // ---- phase A: scores for up to 16 edges x 4 heads across the wave ----
            int s = (eidx < cnt) ? esrc[beg + cb + eidx] : 0;
            float el = (eidx < cnt) ? a_s[s * 4 + h] + ad : -3.0e38f;
            el = fmaxf(el, 0.2f * el);
            float cm = el;
            cm = fmaxf(cm, __shfl_xor(cm, 1));
            cm = fmaxf(cm, __shfl_xor(cm, 2));
            cm = fmaxf(cm, __shfl_xor(cm, 4));
            cm = fmaxf(cm, __shfl_xor(cm, 8));
            float nm = fmaxf(mx, cm);
            if (__any(nm > mx)) {
                float corr = exp2f(mx - nm);     // lanes w/o new max: exp2(0)=1; first chunk: exp2(-inf)=0 on 0 accums
                ssum *= corr; ax *= corr; ay *= corr; az *= corr; aw *= corr;
                mx = nm;
            }
            float p = exp2f(el - mx);            // invalid lanes -> 0
            float cs = p;
            cs += __shfl_xor(cs, 1);
            cs += __shfl_xor(cs, 2);
            cs += __shfl_xor(cs, 4);
            cs += __shfl_xor(cs, 8);
            ssum += cs;
            // ---- phase B: PV with p broadcast ----
            int e2 = 0;
            for (; e2 + 2 <= cnt; e2 += 2) {
                int s0 = __shfl(s, e2), s1 = __shfl(s, e2 + 1);
                float p0 = __shfl(p, (lane & 48) | e2);
                float p1 = __shfl(p, (lane & 48) | (e2 + 1));
                const ushort4 h0 = *reinterpret_cast<const ushort4*>(Hbf + (size_t)s0 * 256 + lane * 4);
                const ushort4 h1 = *reinterpret_cast<const ushort4*>(Hbf + (size_t)s1 * 256 + lane * 4);
                ax += p0 * bf2f(h0.x) + p1 * bf2f(h1.x);
                ay += p0 * bf2f(h0.y) + p1 * bf2f(h1.y);
                az += p0 * bf2f(h0.z) + p1 * bf2f(h1.z);
                aw += p0 * bf2f(h0.w) + p1 * bf2f(h1.w);
            }
            if (e2 < cnt) {
                int s0 = __shfl(s, e2);
                float p0 = __shfl(p, (lane & 48) | e2);
                const ushort4 h0 = *reinterpret_cast<const ushort4*>(Hbf + (size_t)s0 * 256 + lane * 4);
                ax += p0 * bf2f(h0.x);
                ay += p0 * bf2f(h0.y);
                az += p0 * bf2f(h0.z);
                aw += p0 * bf2f(h0.w);
            }
        }

        float inv = 1.0f / ssum;
        const float4 bv = *reinterpret_cast<const float4*>(bias + lane * 4);
        float o0 = fmaxf(ax * inv + bv.x, 0.f);
        float o1 = fmaxf(ay * inv + bv.y, 0.f);
        float o2 = fmaxf(az * inv + bv.z, 0.f);
        float o3 = fmaxf(aw * inv + bv.w, 0.f);
        ushort4 ob; ob.x = f2bf(o0); ob.y = f2bf(o1); ob.z = f2bf(o2); ob.w = f2bf(o3);
        *reinterpret_cast<ushort4*>(outbf + (size_t)wid * 256 + lane * 4) = ob;

        // fused pool
        int g = batch[wid];
        int g0 = batch[nodeBase];
        int slot = g - g0;
        int c4 = lane * 4;
        if (slot < 2) {
            atomicMax(&lpool[slot][c4],     __float_as_int(o0));
            atomicMax(&lpool[slot][c4 + 1], __float_as_int(o1));
            atomicMax(&lpool[slot][c4 + 2], __float_as_int(o2));
            atomicMax(&lpool[slot][c4 + 3], __float_as_int(o3));
        } else {
            int* cell = &gbuf[g * GCOLS + poolOff + c4];
            atomicMax(cell,     __float_as_int(o0));
            atomicMax(cell + 1, __float_as_int(o1));
            atomicMax(cell + 2, __float_as_int(o2));
            atomicMax(cell + 3, __float_as_int(o3));
        }
    }
    __syncthreads();
    if (threadIdx.x < 512) {
        int slot = threadIdx.x >> 8, c = threadIdx.x & 255;
        int v = lpool[slot][c];
        if (v != 0) {
            int g0 = batch[nodeBase];
            atomicMax(&gbuf[(g0 + slot) * GCOLS + poolOff + c], v);
        }
    }
}

// ---------------- fused head ----------------
__global__ __launch_bounds__(256) void k_head(const int* __restrict__ gbuf,
                                              const float* __restrict__ aggW, const float* __restrict__ aggb,
                                              const float* __restrict__ muW, const float* __restrict__ mub,
                                              const float* __restrict__ varW, const float* __restrict__ varb,
                                              float* __restrict__ out) {
    __shared__ float lat[LATD];
    int gi = blockIdx.x, j = threadIdx.x;
    const float* g = (const float*)gbuf + (size_t)gi * GCOLS;
    float acc = aggb[j];
    for (int k = 0; k < GCOLS; ++k) acc += g[k] * aggW[k * 256 + j];
    lat[j] = acc;
    __syncthreads();
    float am = mub[j], av = varb[j];
    for (int k = 0; k < 256; ++k) {
        float l = lat[k];
        am += l * muW[k * 256 + j];
        av += l * varW[k * 256 + j];
    }
    out[(size_t)gi * 256 + j] = am;
    out[(size_t)GG * 256 + (size_t)gi * 256 + j] = av;
}

extern "C" void kernel_launch(void* const* d_in, const int* in_sizes, int n_in,
                              void* d_out, int out_size, void* d_ws, size_t ws_size,
                              hipStream_t stream) {
    const float* bf   = (const float*)d_in[0];
    const int*   ei   = (const int*)d_in[1];
    const int*   batch= (const int*)d_in[2];
    const float* bf_W = (const float*)d_in[3];
    const float* bf_b = (const float*)d_in[4];
    const float* W1   = (const float*)d_in[5];
    const float* as1  = (const float*)d_in[6];
    const float* ad1  = (const float*)d_in[7];
    const float* b1   = (const float*)d_in[8];
    const float* W2   = (const float*)d_in[9];
    const float* as2  = (const float*)d_in[10];
    const float* ad2  = (const float*)d_in[11];
    const float* b2   = (const float*)d_in[12];
    const float* W3   = (const float*)d_in[13];
    const float* as3  = (const float*)d_in[14];
    const float* ad3  = (const float*)d_in[15];
    const float* b3   = (const float*)d_in[16];
    const float* aggW = (const float*)d_in[17];
    const float* aggb = (const float*)d_in[18];
    const float* muW  = (const float*)d_in[19];
    const float* mub  = (const float*)d_in[20];
    const float* varW = (const float*)d_in[21];
    const float* varb = (const float*)d_in[22];
    float* out = (float*)d_out;

    size_t off = 0;
    auto alloc = [&](size_t bytes) -> char* {
        char* p = (char*)d_ws + off;
        off += (bytes + 255) & ~(size_t)255;
        return p;
    };
    // counts and gbuf adjacent -> single memset
    int*   counts  = (int*)alloc((size_t)(NN + GG * GCOLS) * 4);
    int*   gbuf    = counts + NN;
    u16*   Hbf     = (u16*)alloc((size_t)NPAD * 256 * 2);
    u16*   n0bf    = (u16*)alloc((size_t)NPAD * 64 * 2);
    u16*   nbf     = (u16*)alloc((size_t)NPAD * 256 * 2);
    float* a_s     = (float*)alloc((size_t)NPAD * 4 * 4);
    float* a_d     = (float*)alloc((size_t)NPAD * 4 * 4);
    int*   scanned = (int*)alloc((size_t)NN * 4);
    int*   bsums   = (int*)alloc(256 * 4);
    int*   indptr  = (int*)alloc((size_t)(NN + 1) * 4);
    int*   fill    = (int*)alloc((size_t)NN * 4);
    int*   esrc    = (int*)alloc((size_t)ETOT * 4);
    u16*   Wt1     = (u16*)alloc((size_t)256 * 64 * 2);
    u16*   Wt2     = (u16*)alloc((size_t)256 * 256 * 2);
    u16*   Wt3     = (u16*)alloc((size_t)256 * 256 * 2);

    hipMemsetAsync(counts, 0, (size_t)(NN + GG * GCOLS) * 4, stream);

    // prep: wt (576) | n0+pool (391) | count (1368) | pad zero (1)
    k_prep<<<2336, 256, 0, stream>>>(W1, W2, W3, Wt1, Wt2, Wt3,
                                     bf, bf_W, bf_b, batch, n0bf, gbuf,
                                     ei, counts, nbf);

    k_scan_block<<<NB_SCAN, 256, 0, stream>>>(counts, scanned, bsums, NN);
    k_scan_add2<<<NB_SCAN, 256, 0, stream>>>(scanned, bsums, indptr, fill);
    k_fill<<<(ETOT + 255) / 256, 256, 0, stream>>>(ei, indptr, fill, esrc);

    dim3 ggrid(NPAD / BM, 256 / BN);     // (391, 2)
    const int AB = NN / 16;              // 3125

    // ---- layer 1 (K=64) ----
    k_gemm_mfma<<<ggrid, 256, 0, stream>>>(n0bf, Wt1, as1, ad1, Hbf, a_s, a_d, 64);
    k_agg<<<AB, 1024, 0, stream>>>(Hbf, a_s, a_d, indptr, esrc, b1, batch, nbf, gbuf, 64);

    // ---- layer 2 (K=256) ----
    k_gemm_mfma<<<ggrid, 256, 0, stream>>>(nbf, Wt2, as2, ad2, Hbf, a_s, a_d, 256);
    k_agg<<<AB, 1024, 0, stream>>>(Hbf, a_s, a_d, indptr, esrc, b2, batch, nbf, gbuf, 320);

    // ---- layer 3 (K=256) ----
    k_gemm_mfma<<<ggrid, 256, 0, stream>>>(nbf, Wt3, as3, ad3, Hbf, a_s, a_d, 256);
    k_agg<<<AB, 1024, 0, stream>>>(Hbf, a_s, a_d, indptr, esrc, b3, batch, nbf, gbuf, 576);

    // ---- head ----
    k_head<<<GG, 256, 0, stream>>>(gbuf, aggW, aggb, muW, mub, varW, varb, out);
}

// Round 6
// 273.755 us; speedup vs baseline: 6.3993x; 1.0077x over previous
//
#include <hip/hip_runtime.h>
#include <hip/hip_bf16.h>

#define NN 50000
#define NPAD 50048              // 391 * 128
#define EE 300000
#define ETOT (EE + NN)          // 350000 edges incl self-loops
#define GG 64
#define GCOLS 832               // 64 + 3*256
#define LATD 256
#define BM 128
#define BN 128
#define NB_SCAN 196             // (NN+255)/256
#define LOG2E 1.4426950408889634f

typedef unsigned short u16;
typedef short s16x8 __attribute__((ext_vector_type(8)));
typedef float f32x4 __attribute__((ext_vector_type(4)));

__device__ __forceinline__ u16 f2bf(float f) {
    union { float f; unsigned u; } v; v.f = f;
    unsigned r = v.u + 0x7FFFu + ((v.u >> 16) & 1u);
    return (u16)(r >> 16);
}
__device__ __forceinline__ float bf2f(u16 u) {
    union { unsigned u; float f; } v; v.u = ((unsigned)u) << 16;
    return v.f;
}

// ---------------- prep: weight transposes | n0+pool | edge count | pad zero ----------------
__global__ __launch_bounds__(256) void k_prep(const float* __restrict__ W1, const float* __restrict__ W2,
                                              const float* __restrict__ W3, u16* __restrict__ Wt1,
                                              u16* __restrict__ Wt2, u16* __restrict__ Wt3,
                                              const float* __restrict__ bf, const float* __restrict__ Wb,
                                              const float* __restrict__ bb, const int* __restrict__ batch,
                                              u16* __restrict__ n0bf, int* __restrict__ gbuf,
                                              const int* __restrict__ ei, int* __restrict__ counts,
                                              u16* __restrict__ nbf) {
    int b = blockIdx.x;
    if (b < 576) {
        int idx = b * 256 + threadIdx.x;
        if (idx < 16384) {
            int n = idx >> 6, k = idx & 63;
            Wt1[idx] = f2bf(W1[k * 256 + n]);
        } else if (idx < 81920) {
            int t = idx - 16384; int n = t >> 8, k = t & 255;
            Wt2[t] = f2bf(W2[k * 256 + n]);
        } else {
            int t = idx - 81920; int n = t >> 8, k = t & 255;
            Wt3[t] = f2bf(W3[k * 256 + n]);
        }
    } else if (b < 967) {
        int c = threadIdx.x & 63;
        int sub = threadIdx.x >> 6;
        int base = (b - 576) * 128;
        int end = min(base + 128, NN);
        float w0 = Wb[c], w1 = Wb[64 + c], w2 = Wb[128 + c], w3 = Wb[192 + c], w4 = Wb[256 + c], bb_ = bb[c];
        float mx = 0.f;
        int curg = -1;
        for (int n = base + sub; n < end; n += 4) {
            const float* r = bf + (size_t)n * 5;
            float v = bb_ + r[0] * w0 + r[1] * w1 + r[2] * w2 + r[3] * w3 + r[4] * w4;
            v = fmaxf(v, 0.f);
            n0bf[(size_t)n * 64 + c] = f2bf(v);
            int g = batch[n];
            if (g != curg) {
                if (curg >= 0) atomicMax(&gbuf[curg * GCOLS + c], __float_as_int(mx));
                mx = 0.f; curg = g;
            }
            mx = fmaxf(mx, v);
        }
        if (curg >= 0) atomicMax(&gbuf[curg * GCOLS + c], __float_as_int(mx));
    } else if (b < 2335) {
        int e = (b - 967) * 256 + threadIdx.x;
        if (e < ETOT) {
            int d = (e < EE) ? ei[EE + e] : (e - EE);
            atomicAdd(&counts[d], 1);
        }
    } else {
        u16* p0 = n0bf + (size_t)NN * 64;
        for (int i = threadIdx.x; i < (NPAD - NN) * 64; i += 256) p0[i] = 0;
        u16* p1 = nbf + (size_t)NN * 256;
        for (int i = threadIdx.x; i < (NPAD - NN) * 256; i += 256) p1[i] = 0;
    }
}

// ---------------- CSR scan ----------------
__global__ __launch_bounds__(256) void k_scan_block(const int* __restrict__ counts, int* __restrict__ scanned,
                                                    int* __restrict__ bsums, int n) {
    __shared__ int sh[256];
    int i = blockIdx.x * 256 + threadIdx.x;
    int v = (i < n) ? counts[i] : 0;
    sh[threadIdx.x] = v; __syncthreads();
    for (int d = 1; d < 256; d <<= 1) {
        int t = (threadIdx.x >= d) ? sh[threadIdx.x - d] : 0;
        __syncthreads();
        sh[threadIdx.x] += t;
        __syncthreads();
    }
    if (i < n) scanned[i] = sh[threadIdx.x] - v;
    if (threadIdx.x == 255) bsums[blockIdx.x] = sh[255];
}

__global__ __launch_bounds__(256) void k_scan_add2(const int* __restrict__ scanned, const int* __restrict__ bsums,
                                                   int* __restrict__ indptr, int* __restrict__ fill) {
    __shared__ int sh[256];
    int t = threadIdx.x;
    int v = (t < NB_SCAN) ? bsums[t] : 0;
    sh[t] = v; __syncthreads();
    for (int d = 1; d < 256; d <<= 1) {
        int u = (t >= d) ? sh[t - d] : 0;
        __syncthreads();
        sh[t] += u;
        __syncthreads();
    }
    int bix = blockIdx.x;
    int boff = (bix == 0) ? 0 : sh[bix - 1];
    int i = bix * 256 + t;
    if (i < NN) { indptr[i] = scanned[i] + boff; fill[i] = 0; }
    if (i == 0) indptr[NN] = ETOT;
}

__global__ __launch_bounds__(256) void k_fill(const int* __restrict__ ei, const int* __restrict__ indptr,
                                              int* __restrict__ fill, int* __restrict__ esrc) {
    int e = blockIdx.x * 256 + threadIdx.x;
    if (e >= ETOT) return;
    int s, d;
    if (e < EE) { s = ei[e]; d = ei[EE + e]; } else { s = d = e - EE; }
    int pos = atomicAdd(&fill[d], 1);
    esrc[indptr[d] + pos] = s;
}

// ---------------- bf16 MFMA GEMM + fused a_s/a_d epilogue (scores pre-scaled by log2e) ----------------
__global__ __launch_bounds__(256) void k_gemm_mfma(const u16* __restrict__ A,
                                                   const u16* __restrict__ Bt,
                                                   const float* __restrict__ att_s,
                                                   const float* __restrict__ att_d,
                                                   u16* __restrict__ Hbf,
                                                   float* __restrict__ a_s,
                                                   float* __restrict__ a_d,
                                                   int K) {
    __shared__ __align__(16) u16 As[128 * 64];
    __shared__ __align__(16) u16 Bs[128 * 64];
    const int tid = threadIdx.x;
    const int lane = tid & 63;
    const int w = tid >> 6;
    const int wr = w >> 1, wc = w & 1;
    const int row0 = blockIdx.x * BM;
    const int col0 = blockIdx.y * BN;

    f32x4 acc[4][4] = {};

    for (int kt = 0; kt < K; kt += 64) {
#pragma unroll
        for (int i = 0; i < 4; ++i) {
            int u = i * 256 + tid;
            int r = u >> 3, c16 = u & 7;
            int sc = ((c16 ^ (r & 7)) << 3);
            const u16* ga = A + (size_t)(row0 + r) * K + kt + sc;
            u16* la = &As[(size_t)(i * 256 + (w << 6)) * 8];
            __builtin_amdgcn_global_load_lds((const __attribute__((address_space(1))) void*)ga,
                                             (__attribute__((address_space(3))) void*)la, 16, 0, 0);
        }
#pragma unroll
        for (int i = 0; i < 4; ++i) {
            int u = i * 256 + tid;
            int r = u >> 3, c16 = u & 7;
            int sc = ((c16 ^ (r & 7)) << 3);
            const u16* gb = Bt + (size_t)(col0 + r) * K + kt + sc;
            u16* lb = &Bs[(size_t)(i * 256 + (w << 6)) * 8];
            __builtin_amdgcn_global_load_lds((const __attribute__((address_space(1))) void*)gb,
                                             (__attribute__((address_space(3))) void*)lb, 16, 0, 0);
        }
        __syncthreads();
#pragma unroll
        for (int ks = 0; ks < 2; ++ks) {
            s16x8 af[4], bfr[4];
#pragma unroll
            for (int m = 0; m < 4; ++m) {
                int ra = wr * 64 + m * 16 + (lane & 15);
                int c16 = ks * 4 + (lane >> 4);
                int off = ra * 64 + ((c16 ^ (ra & 7)) << 3);
                af[m] = *reinterpret_cast<const s16x8*>(&As[off]);
            }
#pragma unroll
            for (int n = 0; n < 4; ++n) {
                int rb = wc * 64 + n * 16 + (lane & 15);
                int c16 = ks * 4 + (lane >> 4);
                int off = rb * 64 + ((c16 ^ (rb & 7)) << 3);
                bfr[n] = *reinterpret_cast<const s16x8*>(&Bs[off]);
            }
#pragma unroll
            for (int m = 0; m < 4; ++m)
#pragma unroll
                for (int n = 0; n < 4; ++n)
                    acc[m][n] = __builtin_amdgcn_mfma_f32_16x16x32_bf16(af[m], bfr[n], acc[m][n], 0, 0, 0);
        }
        __syncthreads();
    }

    const int head = (blockIdx.y << 1) + wc;
    float asv[4], adv[4];
#pragma unroll
    for (int n = 0; n < 4; ++n) {
        asv[n] = att_s[head * 64 + n * 16 + (lane & 15)] * LOG2E;
        adv[n] = att_d[head * 64 + n * 16 + (lane & 15)] * LOG2E;
    }
#pragma unroll
    for (int m = 0; m < 4; ++m) {
        int growb = row0 + wr * 64 + m * 16 + (lane >> 4) * 4;
#pragma unroll
        for (int j = 0; j < 4; ++j) {
            int grow = growb + j;
            u16* orow = Hbf + (size_t)grow * 256 + col0 + wc * 64 + (lane & 15);
            float vs = 0.f, vd = 0.f;
#pragma unroll
            for (int n = 0; n < 4; ++n) {
                float v = acc[m][n][j];
                orow[n * 16] = f2bf(v);
                vs += v * asv[n];
                vd += v * adv[n];
            }
            vs += __shfl_xor(vs, 1); vd += __shfl_xor(vd, 1);
            vs += __shfl_xor(vs, 2); vd += __shfl_xor(vd, 2);
            vs += __shfl_xor(vs, 4); vd += __shfl_xor(vd, 4);
            vs += __shfl_xor(vs, 8); vd += __shfl_xor(vd, 8);
            if ((lane & 15) == 0) {
                a_s[grow * 4 + head] = vs;
                a_d[grow * 4 + head] = vd;
            }
        }
    }
}

// ---------------- two-phase online-softmax aggregate + fused pool (atomic-free LDS) ----------------
// block = 512 thr = 8 waves = 8 consecutive nodes (batch-sorted). NN % 8 == 0 -> no guards.
__global__ __launch_bounds__(512) void k_agg(const u16* __restrict__ Hbf, const float* __restrict__ a_s,
                                             const float* __restrict__ a_d, const int* __restrict__ indptr,
                                             const int* __restrict__ esrc, const float* __restrict__ bias,
                                             const int* __restrict__ batch, u16* __restrict__ outbf,
                                             int* __restrict__ gbuf, int poolOff) {
    __shared__ float smax[8][256];
    __shared__ int sb[8];
    const int nodeBase = blockIdx.x * 8;
    const int wv = threadIdx.x >> 6;
    const int wid = nodeBase + wv;
    const int lane = threadIdx.x & 63;
    const int h = lane >> 4;
    const int eidx = lane & 15;

    if (threadIdx.x < 8) sb[threadIdx.x] = batch[nodeBase + threadIdx.x];
    __syncthreads();

    int beg = indptr[wid];
    int dcount = indptr[wid + 1] - beg;
    float ad = a_d[wid * 4 + h];
    float mx = -3.0e38f, ssum = 0.f;
    float ax = 0.f, ay = 0.f, az = 0.f, aw = 0.f;

    for (int cb = 0; cb < dcount; cb += 16) {
        int cnt = min(16, dcount - cb);
        // ---- phase A: scores for up to 16 edges x 4 heads across the wave ----
        int s = (eidx < cnt) ? esrc[beg + cb + eidx] : 0;
        float el = (eidx < cnt) ? a_s[s * 4 + h] + ad : -3.0e38f;
        el = fmaxf(el, 0.2f * el);
        float cm = el;
        cm = fmaxf(cm, __shfl_xor(cm, 1));
        cm = fmaxf(cm, __shfl_xor(cm, 2));
        cm = fmaxf(cm, __shfl_xor(cm, 4));
        cm = fmaxf(cm, __shfl_xor(cm, 8));
        float nm = fmaxf(mx, cm);
        if (__any(nm > mx)) {
            float corr = exp2f(mx - nm);
            ssum *= corr; ax *= corr; ay *= corr; az *= corr; aw *= corr;
            mx = nm;
        }
        float p = exp2f(el - mx);
        float cs = p;
        cs += __shfl_xor(cs, 1);
        cs += __shfl_xor(cs, 2);
        cs += __shfl_xor(cs, 4);
        cs += __shfl_xor(cs, 8);
        ssum += cs;
        // ---- phase B: PV, 4-wide unroll for load depth ----
        int e2 = 0;
        for (; e2 + 4 <= cnt; e2 += 4) {
            int s0 = __shfl(s, e2), s1 = __shfl(s, e2 + 1), s2 = __shfl(s, e2 + 2), s3 = __shfl(s, e2 + 3);
            float p0 = __shfl(p, (lane & 48) | e2);
            float p1 = __shfl(p, (lane & 48) | (e2 + 1));
            float p2 = __shfl(p, (lane & 48) | (e2 + 2));
            float p3 = __shfl(p, (lane & 48) | (e2 + 3));
            const ushort4 h0 = *reinterpret_cast<const ushort4*>(Hbf + (size_t)s0 * 256 + lane * 4);
            const ushort4 h1 = *reinterpret_cast<const ushort4*>(Hbf + (size_t)s1 * 256 + lane * 4);
            const ushort4 h2 = *reinterpret_cast<const ushort4*>(Hbf + (size_t)s2 * 256 + lane * 4);
            const ushort4 h3 = *reinterpret_cast<const ushort4*>(Hbf + (size_t)s3 * 256 + lane * 4);
            ax += p0 * bf2f(h0.x) + p1 * bf2f(h1.x) + p2 * bf2f(h2.x) + p3 * bf2f(h3.x);
            ay += p0 * bf2f(h0.y) + p1 * bf2f(h1.y) + p2 * bf2f(h2.y) + p3 * bf2f(h3.y);
            az += p0 * bf2f(h0.z) + p1 * bf2f(h1.z) + p2 * bf2f(h2.z) + p3 * bf2f(h3.z);
            aw += p0 * bf2f(h0.w) + p1 * bf2f(h1.w) + p2 * bf2f(h2.w) + p3 * bf2f(h3.w);
        }
        for (; e2 < cnt; ++e2) {
            int s0 = __shfl(s, e2);
            float p0 = __shfl(p, (lane & 48) | e2);
            const ushort4 h0 = *reinterpret_cast<const ushort4*>(Hbf + (size_t)s0 * 256 + lane * 4);
            ax += p0 * bf2f(h0.x);
            ay += p0 * bf2f(h0.y);
            az += p0 * bf2f(h0.z);
            aw += p0 * bf2f(h0.w);
        }
    }

    float inv = 1.0f / ssum;
    const float4 bv = *reinterpret_cast<const float4*>(bias + lane * 4);
    float o0 = fmaxf(ax * inv + bv.x, 0.f);
    float o1 = fmaxf(ay * inv + bv.y, 0.f);
    float o2 = fmaxf(az * inv + bv.z, 0.f);
    float o3 = fmaxf(aw * inv + bv.w, 0.f);
    ushort4 ob; ob.x = f2bf(o0); ob.y = f2bf(o1); ob.z = f2bf(o2); ob.w = f2bf(o3);
    *reinterpret_cast<ushort4*>(outbf + (size_t)wid * 256 + lane * 4) = ob;

    // pool: LDS row store (no atomics)
    *reinterpret_cast<float4*>(&smax[wv][lane * 4]) = make_float4(o0, o1, o2, o3);
    int slot = sb[wv] - sb[0];
    if (slot >= 2) {   // rare: >2 graphs in an 8-node window
        int* cell = &gbuf[sb[wv] * GCOLS + poolOff + lane * 4];
        atomicMax(cell,     __float_as_int(o0));
        atomicMax(cell + 1, __float_as_int(o1));
        atomicMax(cell + 2, __float_as_int(o2));
        atomicMax(cell + 3, __float_as_int(o3));
    }
    __syncthreads();

    // flush: 512 threads = 2 graph slots x 256 channels
    int slotf = threadIdx.x >> 8;
    int c = threadIdx.x & 255;
    int gtar = sb[0] + slotf;
    float m = 0.f;
#pragma unroll
    for (int n = 0; n < 8; ++n)
        if (sb[n] == gtar) m = fmaxf(m, smax[n][c]);
    if (m > 0.f) atomicMax(&gbuf[gtar * GCOLS + poolOff + c], __float_as_int(m));
}

// ---------------- fused head: 1024 thr, k-split 4-ways ----------------
__global__ __launch_bounds__(1024) void k_head(const int* __restrict__ gbuf,
                                               const float* __restrict__ aggW, const float* __restrict__ aggb,
                                               const float* __restrict__ muW, const float* __restrict__ mub,
                                               const float* __restrict__ varW, const float* __restrict__ varb,
                                               float* __restrict__ out) {
    __shared__ float part[4][256];
    __shared__ float lat[LATD];
    int gi = blockIdx.x;
    int j = threadIdx.x & 255, ks = threadIdx.x >> 8;
    const float* g = (const float*)gbuf + (size_t)gi * GCOLS;
    float acc = 0.f;
    int k0 = ks * 208;
    for (int k = k0; k < k0 + 208; ++k) acc += g[k] * aggW[k * 256 + j];
    part[ks][j] = acc;
    __syncthreads();
    if (ks == 0) lat[j] = part[0][j] + part[1][j] + part[2][j] + part[3][j] + aggb[j];
    __syncthreads();
    const float* W = (ks < 2) ? muW : varW;
    int kb = (ks & 1) * 128;
    float am = 0.f;
    for (int k = kb; k < kb + 128; ++k) am += lat[k] * W[k * 256 + j];
    part[ks][j] = am;
    __syncthreads();
    if (ks == 0) out[(size_t)gi * 256 + j] = part[0][j] + part[1][j] + mub[j];
    else if (ks == 1) out[(size_t)GG * 256 + (size_t)gi * 256 + j] = part[2][j] + part[3][j] + varb[j];
}

extern "C" void kernel_launch(void* const* d_in, const int* in_sizes, int n_in,
                              void* d_out, int out_size, void* d_ws, size_t ws_size,
                              hipStream_t stream) {
    const float* bf   = (const float*)d_in[0];
    const int*   ei   = (const int*)d_in[1];
    const int*   batch= (const int*)d_in[2];
    const float* bf_W = (const float*)d_in[3];
    const float* bf_b = (const float*)d_in[4];
    const float* W1   = (const float*)d_in[5];
    const float* as1  = (const float*)d_in[6];
    const float* ad1  = (const float*)d_in[7];
    const float* b1   = (const float*)d_in[8];
    const float* W2   = (const float*)d_in[9];
    const float* as2  = (const float*)d_in[10];
    const float* ad2  = (const float*)d_in[11];
    const float* b2   = (const float*)d_in[12];
    const float* W3   = (const float*)d_in[13];
    const float* as3  = (const float*)d_in[14];
    const float* ad3  = (const float*)d_in[15];
    const float* b3   = (const float*)d_in[16];
    const float* aggW = (const float*)d_in[17];
    const float* aggb = (const float*)d_in[18];
    const float* muW  = (const float*)d_in[19];
    const float* mub  = (const float*)d_in[20];
    const float* varW = (const float*)d_in[21];
    const float* varb = (const float*)d_in[22];
    float* out = (float*)d_out;

    size_t off = 0;
    auto alloc = [&](size_t bytes) -> char* {
        char* p = (char*)d_ws + off;
        off += (bytes + 255) & ~(size_t)255;
        return p;
    };
    int*   counts  = (int*)alloc((size_t)(NN + GG * GCOLS) * 4);
    int*   gbuf    = counts + NN;
    u16*   Hbf     = (u16*)alloc((size_t)NPAD * 256 * 2);
    u16*   n0bf    = (u16*)alloc((size_t)NPAD * 64 * 2);
    u16*   nbf     = (u16*)alloc((size_t)NPAD * 256 * 2);
    float* a_s     = (float*)alloc((size_t)NPAD * 4 * 4);
    float* a_d     = (float*)alloc((size_t)NPAD * 4 * 4);
    int*   scanned = (int*)alloc((size_t)NN * 4);
    int*   bsums   = (int*)alloc(256 * 4);
    int*   indptr  = (int*)alloc((size_t)(NN + 1) * 4);
    int*   fill    = (int*)alloc((size_t)NN * 4);
    int*   esrc    = (int*)alloc((size_t)ETOT * 4);
    u16*   Wt1     = (u16*)alloc((size_t)256 * 64 * 2);
    u16*   Wt2     = (u16*)alloc((size_t)256 * 256 * 2);
    u16*   Wt3     = (u16*)alloc((size_t)256 * 256 * 2);

    hipMemsetAsync(counts, 0, (size_t)(NN + GG * GCOLS) * 4, stream);

    k_prep<<<2336, 256, 0, stream>>>(W1, W2, W3, Wt1, Wt2, Wt3,
                                     bf, bf_W, bf_b, batch, n0bf, gbuf,
                                     ei, counts, nbf);

    k_scan_block<<<NB_SCAN, 256, 0, stream>>>(counts, scanned, bsums, NN);
    k_scan_add2<<<NB_SCAN, 256, 0, stream>>>(scanned, bsums, indptr, fill);
    k_fill<<<(ETOT + 255) / 256, 256, 0, stream>>>(ei, indptr, fill, esrc);

    dim3 ggrid(NPAD / BM, 256 / BN);     // (391, 2)
    const int AB = NN / 8;               // 6250

    // ---- layer 1 (K=64) ----
    k_gemm_mfma<<<ggrid, 256, 0, stream>>>(n0bf, Wt1, as1, ad1, Hbf, a_s, a_d, 64);
    k_agg<<<AB, 512, 0, stream>>>(Hbf, a_s, a_d, indptr, esrc, b1, batch, nbf, gbuf, 64);

    // ---- layer 2 (K=256) ----
    k_gemm_mfma<<<ggrid, 256, 0, stream>>>(nbf, Wt2, as2, ad2, Hbf, a_s, a_d, 256);
    k_agg<<<AB, 512, 0, stream>>>(Hbf, a_s, a_d, indptr, esrc, b2, batch, nbf, gbuf, 320);

    // ---- layer 3 (K=256) ----
    k_gemm_mfma<<<ggrid, 256, 0, stream>>>(nbf, Wt3, as3, ad3, Hbf, a_s, a_d, 256);
    k_agg<<<AB, 512, 0, stream>>>(Hbf, a_s, a_d, indptr, esrc, b3, batch, nbf, gbuf, 576);

    // ---- head ----
    k_head<<<GG, 1024, 0, stream>>>(gbuf, aggW, aggb, muW, mub, varW, varb, out);
}